// Round 9
// baseline (8247.304 us; speedup 1.0000x reference)
//
#include <hip/hip_runtime.h>
#include <hip/hip_bf16.h>

#define T_ 64
#define DETER_ 4096
#define GRUN 12288

typedef __attribute__((ext_vector_type(8))) __bf16 bf16x8;
typedef __attribute__((ext_vector_type(4))) float f32x4;
typedef __attribute__((ext_vector_type(8))) unsigned short u16x8;
typedef __attribute__((ext_vector_type(4))) unsigned short u16x4;

__device__ inline unsigned short f2bf(float f) {
    union { float f; unsigned u; } x; x.f = f;
    unsigned r = x.u + 0x7fffu + ((x.u >> 16) & 1u);
    return (unsigned short)(r >> 16);
}
__device__ inline float sigmoidf_(float v) { return 1.f / (1.f + __expf(-v)); }
__device__ inline float siluf_(float v)    { return v / (1.f + __expf(-v)); }
__device__ inline float softplusf_(float v){ return fmaxf(v, 0.f) + __logf(1.f + __expf(-fabsf(v))); }
__device__ inline float tanhf_(float v)    { return 2.f / (1.f + __expf(-2.f * v)) - 1.f; }

__device__ inline void barrier_() {
    asm volatile("" ::: "memory");
    __builtin_amdgcn_s_barrier();
    asm volatile("" ::: "memory");
}
template <int N> __device__ inline void vmwaitN() {
    asm volatile("s_waitcnt vmcnt(%0)" :: "i"(N) : "memory");
}
__device__ inline void lgkmwait_() {
    asm volatile("s_waitcnt lgkmcnt(0)" ::: "memory");
}

// device-scope flag sync (verified in R7)
__device__ inline void waitflag(int* f, int target) {
    if (threadIdx.x == 0) {
        while (__hip_atomic_load(f, __ATOMIC_ACQUIRE, __HIP_MEMORY_SCOPE_AGENT) < target)
            __builtin_amdgcn_s_sleep(2);
    }
    __syncthreads();
}
__device__ inline void postflag(int* f) {
    __syncthreads();
    if (threadIdx.x == 0)
        __hip_atomic_fetch_add(f, 1, __ATOMIC_RELEASE, __HIP_MEMORY_SCOPE_AGENT);
}

// ---------------- prep kernels ----------------

__global__ __launch_bounds__(256) void k_pack(const float* __restrict__ W,
                                              unsigned short* __restrict__ dst,
                                              int K, int N) {
    long fid = (long)blockIdx.x * 256 + threadIdx.x;
    long nfr = (long)K * N / 8;
    if (fid >= nfr) return;
    int lane = (int)(fid & 63);
    long tile = fid >> 6;
    int ktiles = K >> 5;
    int k_t = (int)(tile % ktiles);
    int n_t = (int)(tile / ktiles);
    int c = lane & 15, kb = lane >> 4;
    int k0 = k_t * 32 + kb * 8;
    int n = n_t * 16 + c;
    unsigned short v[8];
#pragma unroll
    for (int i = 0; i < 8; i++) v[i] = f2bf(W[(long)(k0 + i) * N + n]);
    *reinterpret_cast<u16x8*>(dst + fid * 8) = *reinterpret_cast<u16x8*>(v);
}

__global__ __launch_bounds__(256) void k_conv(const float* __restrict__ s,
                                              unsigned short* __restrict__ d, long n) {
    long i = ((long)blockIdx.x * 256 + threadIdx.x) * 4;
    if (i >= n) return;
    f32x4 v = *reinterpret_cast<const f32x4*>(s + i);
    unsigned short o[4];
#pragma unroll
    for (int k = 0; k < 4; k++) o[k] = f2bf(v[k]);
    *reinterpret_cast<u16x4*>(d + i) = *reinterpret_cast<u16x4*>(o);
}

__global__ __launch_bounds__(256) void k_copy(const float* __restrict__ s,
                                              float* __restrict__ d, long n) {
    long i = ((long)blockIdx.x * 256 + threadIdx.x) * 4;
    if (i >= n) return;
    *reinterpret_cast<f32x4*>(d + i) = *reinterpret_cast<const f32x4*>(s + i);
}

__global__ void k_zeroflags(int* f, int n) {
    int i = blockIdx.x * 256 + threadIdx.x;
    if (i < n) f[i] = 0;
}

// ---------------- staging helpers (R4-verified) ----------------

template <int CW>
__device__ inline void stage_glds(unsigned short* chunk, const unsigned short* __restrict__ src,
                                  long ld, long k0) {
    constexpr int NI = (32 * CW * 2) / 4096;
    int wv = (int)threadIdx.x >> 6, lane = (int)threadIdx.x & 63;
#pragma unroll
    for (int i = 0; i < NI; ++i) {
        int obase = (wv * NI + i) << 10;
        int o = obase + lane * 16;
        int row = o / (CW * 2);
        int cb = o - row * (CW * 2);
        int gb = cb ^ ((row & 7) << 4);
        const char* ga = (const char*)(src + (long)row * ld + k0) + gb;
        __builtin_amdgcn_global_load_lds(
            (const __attribute__((address_space(1))) void*)ga,
            (__attribute__((address_space(3))) void*)(chunk + (obase >> 1)),
            16, 0, 0);
    }
}

__device__ inline void stage_ln512(unsigned short* chunk, const float* __restrict__ raw,
                                   int ld, int col0,
                                   const float* __restrict__ g, const float* __restrict__ b,
                                   const float* s_mean, const float* s_rstd) {
    int tid = threadIdx.x;
#pragma unroll
    for (int i = 0; i < 8; ++i) {
        int e = tid * 8 + i * 2048;
        int row = e >> 9, col = e & 511;
        float m = s_mean[row], rs = s_rstd[row];
        const float* sp = raw + (long)row * ld + col0 + col;
        unsigned short pk[8];
#pragma unroll
        for (int j = 0; j < 8; ++j) {
            float ln = (sp[j] - m) * rs * g[col0 + col + j] + b[col0 + col + j];
            pk[j] = f2bf(siluf_(ln));
        }
        int dcol = col ^ ((row & 7) << 3);
        *reinterpret_cast<u16x8*>(chunk + row * 512 + dcol) = *reinterpret_cast<u16x8*>(pk);
    }
}

__device__ inline void stage_lnsum(unsigned short* chunk, const float* __restrict__ hpart,
                                   const float* __restrict__ eprep, int t, int col0,
                                   const float* __restrict__ g, const float* __restrict__ b,
                                   const float* s_mean, const float* s_rstd) {
    int tid = threadIdx.x;
#pragma unroll
    for (int i = 0; i < 8; ++i) {
        int e = tid * 8 + i * 2048;
        int row = e >> 9, col = e & 511;
        int k = col0 + col;
        float m = s_mean[row], rs = s_rstd[row];
        const float* h0 = hpart + (long)row * 1024 + k;
        const float* ep = eprep + ((long)row * T_ + t) * 1024 + k;
        unsigned short pk[8];
#pragma unroll
        for (int jj = 0; jj < 8; jj += 4) {
            f32x4 v = *reinterpret_cast<const f32x4*>(h0 + jj);
            v += *reinterpret_cast<const f32x4*>(h0 + 32768 + jj);
            v += *reinterpret_cast<const f32x4*>(h0 + 65536 + jj);
            v += *reinterpret_cast<const f32x4*>(h0 + 98304 + jj);
            v += *reinterpret_cast<const f32x4*>(ep + jj);
#pragma unroll
            for (int j2 = 0; j2 < 4; ++j2) {
                float ln = (v[j2] - m) * rs * g[k + jj + j2] + b[k + jj + j2];
                pk[jj + j2] = f2bf(siluf_(ln));
            }
        }
        int dcol = col ^ ((row & 7) << 3);
        *reinterpret_cast<u16x8*>(chunk + row * 512 + dcol) = *reinterpret_cast<u16x8*>(pk);
    }
}

template <int CW>
__device__ inline void mfma_rh(const unsigned short* chunk, int row, int kb,
                               const unsigned short* __restrict__ bp, f32x4& acc) {
    constexpr int NKT = CW / 32;
    const unsigned short* ap = chunk + row * CW;
    int sw = (row & 7) << 3;
#pragma unroll
    for (int kt = 0; kt < NKT; ++kt) {
        bf16x8 a = *reinterpret_cast<const bf16x8*>(ap + ((kb * 8 + kt * 32) ^ sw));
        bf16x8 b = *reinterpret_cast<const bf16x8*>(bp + (long)kt * 512);
        acc = __builtin_amdgcn_mfma_f32_16x16x32_bf16(a, b, acc, 0, 0, 0);
    }
}

template <int CW>
__device__ inline void mfma2(const unsigned short* chunk, int c, int kb,
                             const unsigned short* __restrict__ bp,
                             f32x4& acc0, f32x4& acc1) {
    constexpr int NKT = CW / 32;
    const unsigned short* ap0 = chunk + c * CW;
    const unsigned short* ap1 = chunk + (16 + c) * CW;
    int sw = (c & 7) << 3;
#pragma unroll
    for (int kt = 0; kt < NKT; ++kt) {
        int off = (kb * 8 + kt * 32) ^ sw;
        bf16x8 b = *reinterpret_cast<const bf16x8*>(bp + (long)kt * 512);
        bf16x8 a0 = *reinterpret_cast<const bf16x8*>(ap0 + off);
        bf16x8 a1 = *reinterpret_cast<const bf16x8*>(ap1 + off);
        acc0 = __builtin_amdgcn_mfma_f32_16x16x32_bf16(a0, b, acc0, 0, 0, 0);
        acc1 = __builtin_amdgcn_mfma_f32_16x16x32_bf16(a1, b, acc1, 0, 0, 0);
    }
}

// ---------------- generic 32-row GEMM (prep / tail; R4-verified) ----------------
template <int CW, int NG, int NL>
__global__ __launch_bounds__(256) void k_gemm32(
    const unsigned short* __restrict__ Bp, int Ktiles, int ktg0,
    const unsigned short* __restrict__ srcA, long ldA,
    const float* __restrict__ lnraw, int lnld,
    const float* __restrict__ g_ln, const float* __restrict__ b_ln,
    const float* __restrict__ pstats, int nslab_in,
    const float* __restrict__ addin, long addin_ld,
    float* __restrict__ outp, long out_ld,
    float* __restrict__ partials, long prows)
{
    constexpr int NCH = NG + NL;
    constexpr int NI = (32 * CW * 2) / 4096;
    __shared__ __align__(16) unsigned short sb[2][32 * CW];
    __shared__ float s_out[32][34];
    __shared__ float s_mean[32], s_rstd[32];
    int tid = threadIdx.x;
    if (NL > 0) {
        if (tid < 32) {
            float s = 0.f, q = 0.f;
            for (int j = 0; j < nslab_in; ++j) {
                s += pstats[((long)j * 32 + tid) * 2];
                q += pstats[((long)j * 32 + tid) * 2 + 1];
            }
            float m = s * (1.f / 1024.f);
            s_mean[tid] = m;
            s_rstd[tid] = rsqrtf(q * (1.f / 1024.f) - m * m + 1e-3f);
        }
        __syncthreads();
    }
    int rowbase = blockIdx.y * 32;
    const unsigned short* srcAr = srcA + (long)rowbase * ldA;
    int lane = tid & 63, wv = tid >> 6;
    int nt = wv >> 1, rh = wv & 1;
    int c = lane & 15, kb = lane >> 4;
    int mrow = rh * 16 + c;
    long ntg = (long)blockIdx.x * 2 + nt;
    const unsigned short* bbase = Bp + (long)ntg * Ktiles * 512 + lane * 8;
    f32x4 acc = {0.f, 0.f, 0.f, 0.f};
    stage_glds<CW>(sb[0], srcAr, ldA, 0);
    for (int ch = 0; ch < NCH; ++ch) {
        int nx = ch + 1;
        if (nx < NG) stage_glds<CW>(sb[nx & 1], srcAr, ldA, (long)nx * CW);
        else if (nx < NCH) stage_ln512(sb[nx & 1], lnraw, lnld, (nx - NG) * 512,
                                       g_ln, b_ln, s_mean, s_rstd);
        if (ch < NG) { if (nx < NG) vmwaitN<NI>(); else vmwaitN<0>(); }
        if (nx >= NG && nx < NCH) lgkmwait_();
        barrier_();
        int kt0 = (ch < NG) ? (ktg0 + ch * (CW / 32)) : ((ch - NG) * 16);
        mfma_rh<CW>(sb[ch & 1], mrow, kb, bbase + (long)kt0 * 512, acc);
        barrier_();
    }
    __syncthreads();
#pragma unroll
    for (int j = 0; j < 4; ++j) s_out[rh * 16 + kb * 4 + j][nt * 16 + c] = acc[j];
    __syncthreads();
    int orow = tid >> 3, c4 = (tid & 7) * 4;
    long rg = rowbase + orow;
    float v[4]; float s = 0.f, q = 0.f;
#pragma unroll
    for (int i = 0; i < 4; ++i) {
        float x = s_out[orow][c4 + i];
        if (addin) x += addin[rg * addin_ld + blockIdx.x * 32 + c4 + i];
        v[i] = x; s += x; q += x * x;
    }
#pragma unroll
    for (int i = 0; i < 4; ++i) outp[rg * out_ld + blockIdx.x * 32 + c4 + i] = v[i];
    if (partials) {
#pragma unroll
        for (int m = 1; m < 8; m <<= 1) { s += __shfl_xor(s, m); q += __shfl_xor(q, m); }
        if ((tid & 7) == 0) {
            partials[((long)blockIdx.x * prows + rg) * 2] = s;
            partials[((long)blockIdx.x * prows + rg) * 2 + 1] = q;
        }
    }
}

// ---------------- fused x + GRU kernel (400 blocks) ----------------
// bid 0..15: X role (R7-verified); bid 16..207: gru khalf0; bid 208..399: khalf1 (R4-verified).
__global__ __launch_bounds__(256) void k_gruxf(
    const unsigned short* __restrict__ pWin_s,
    const unsigned short* __restrict__ pWgru,
    const unsigned short* __restrict__ stochb,
    const unsigned short* __restrict__ deterb,
    const float* __restrict__ A_pre,
    float* __restrict__ x_raw, float* __restrict__ px,
    const float* __restrict__ g_in, const float* __restrict__ b_in,
    float* __restrict__ Gp0, float* __restrict__ Gp1,
    int* __restrict__ fX, int t)
{
    __shared__ __align__(16) unsigned short sb[2][32 * 512];
    __shared__ float s_out[32][66];
    __shared__ float s_mean[32], s_rstd[32];
    int bid = blockIdx.x, tid = threadIdx.x;
    int lane = tid & 63, wv = tid >> 6;
    int c = lane & 15, kb = lane >> 4;

    if (bid < 16) {
        // ---- X role: x_raw = stoch@Win_s + A_pre[t]; px partials (16 slabs) ----
        int xi = bid;
        const unsigned short* bbase = pWin_s + ((long)xi * 4 + wv) * 32 * 512 + lane * 8;
        f32x4 a0 = {0, 0, 0, 0}, a1 = {0, 0, 0, 0};
        stage_glds<512>(sb[0], stochb, 1024, 0);
        stage_glds<512>(sb[1], stochb, 1024, 512);
        vmwaitN<8>(); barrier_();
        mfma2<512>(sb[0], c, kb, bbase, a0, a1);
        vmwaitN<0>(); barrier_();
        mfma2<512>(sb[1], c, kb, bbase + (long)16 * 512, a0, a1);
        __syncthreads();
#pragma unroll
        for (int j = 0; j < 4; ++j) {
            s_out[kb * 4 + j][wv * 16 + c] = a0[j];
            s_out[16 + kb * 4 + j][wv * 16 + c] = a1[j];
        }
        __syncthreads();
        int row = tid >> 3, c8 = (tid & 7) * 8;
        const float* ap = A_pre + ((long)row * T_ + t) * 1024 + xi * 64 + c8;
        float s = 0.f, q = 0.f, v[8];
#pragma unroll
        for (int i = 0; i < 8; ++i) {
            float x = s_out[row][c8 + i] + ap[i];
            v[i] = x; s += x; q += x * x;
        }
#pragma unroll
        for (int i = 0; i < 8; ++i) x_raw[(long)row * 1024 + xi * 64 + c8 + i] = v[i];
#pragma unroll
        for (int m = 1; m < 8; m <<= 1) { s += __shfl_xor(s, m); q += __shfl_xor(q, m); }
        if ((tid & 7) == 0) {
            px[((long)xi * 32 + row) * 2] = s;
            px[((long)xi * 32 + row) * 2 + 1] = q;
        }
        postflag(&fX[t]);
    } else if (bid < 208) {
        // ---- gru khalf0: K = x(LN) 0..1023 + deter 0..1535 ----
        int gb = bid - 16;
        long ntg = (long)gb * 4 + wv;
        const unsigned short* bbase = pWgru + ntg * 160 * 512 + lane * 8;
        f32x4 acc0 = {0, 0, 0, 0}, acc1 = {0, 0, 0, 0};
        stage_glds<512>(sb[0], deterb, 4096, 0);
        stage_glds<512>(sb[1], deterb, 4096, 512);
        vmwaitN<8>(); barrier_();
        mfma2<512>(sb[0], c, kb, bbase + 32 * 512, acc0, acc1);
        barrier_();
        stage_glds<512>(sb[0], deterb, 4096, 1024);
        vmwaitN<8>(); barrier_();
        mfma2<512>(sb[1], c, kb, bbase + 48 * 512, acc0, acc1);
        barrier_();
        // x available by now (overlapped with the 2 deter chunks above)
        waitflag(&fX[t], 16);
        if (tid < 32) {
            float s = 0.f, q = 0.f;
            for (int j = 0; j < 16; ++j) {
                s += px[((long)j * 32 + tid) * 2];
                q += px[((long)j * 32 + tid) * 2 + 1];
            }
            float m = s * (1.f / 1024.f);
            s_mean[tid] = m;
            s_rstd[tid] = rsqrtf(q * (1.f / 1024.f) - m * m + 1e-3f);
        }
        __syncthreads();
        stage_ln512(sb[1], x_raw, 1024, 0, g_in, b_in, s_mean, s_rstd);
        vmwaitN<0>(); barrier_();
        mfma2<512>(sb[0], c, kb, bbase + 64 * 512, acc0, acc1);
        barrier_();
        stage_ln512(sb[0], x_raw, 1024, 512, g_in, b_in, s_mean, s_rstd);
        lgkmwait_(); barrier_();
        mfma2<512>(sb[1], c, kb, bbase + 0, acc0, acc1);
        barrier_();
        mfma2<512>(sb[0], c, kb, bbase + 16 * 512, acc0, acc1);
        __syncthreads();
#pragma unroll
        for (int j = 0; j < 4; ++j) {
            s_out[kb * 4 + j][wv * 16 + c] = acc0[j];
            s_out[16 + kb * 4 + j][wv * 16 + c] = acc1[j];
        }
        __syncthreads();
        int row = tid >> 3, c8 = (tid & 7) * 8;
#pragma unroll
        for (int i = 0; i < 8; ++i)
            Gp0[(long)row * GRUN + gb * 64 + c8 + i] = s_out[row][c8 + i];
    } else {
        // ---- gru khalf1: K = deter 1536..4095 ----
        int gb = bid - 208;
        long ntg = (long)gb * 4 + wv;
        const unsigned short* bbase = pWgru + ntg * 160 * 512 + lane * 8;
        f32x4 acc0 = {0, 0, 0, 0}, acc1 = {0, 0, 0, 0};
        stage_glds<512>(sb[0], deterb, 4096, 1536);
        stage_glds<512>(sb[1], deterb, 4096, 2048);
        vmwaitN<8>(); barrier_();
        mfma2<512>(sb[0], c, kb, bbase + 80 * 512, acc0, acc1);
        barrier_();
        stage_glds<512>(sb[0], deterb, 4096, 2560);
        vmwaitN<8>(); barrier_();
        mfma2<512>(sb[1], c, kb, bbase + 96 * 512, acc0, acc1);
        barrier_();
        stage_glds<512>(sb[1], deterb, 4096, 3072);
        vmwaitN<8>(); barrier_();
        mfma2<512>(sb[0], c, kb, bbase + 112 * 512, acc0, acc1);
        barrier_();
        stage_glds<512>(sb[0], deterb, 4096, 3584);
        vmwaitN<8>(); barrier_();
        mfma2<512>(sb[1], c, kb, bbase + 128 * 512, acc0, acc1);
        barrier_();
        vmwaitN<0>(); barrier_();
        mfma2<512>(sb[0], c, kb, bbase + 144 * 512, acc0, acc1);
        __syncthreads();
#pragma unroll
        for (int j = 0; j < 4; ++j) {
            s_out[kb * 4 + j][wv * 16 + c] = acc0[j];
            s_out[16 + kb * 4 + j][wv * 16 + c] = acc1[j];
        }
        __syncthreads();
        int row = tid >> 3, c8 = (tid & 7) * 8;
#pragma unroll
        for (int i = 0; i < 8; ++i)
            Gp1[(long)row * GRUN + gb * 64 + c8 + i] = s_out[row][c8 + i];
    }
}

// ---------------- fused deter + h + statsq kernel (128 blocks) ----------------
// bid 0..31: D role (R7-verified, Gp0+Gp1 sum); 32..95: H role (R4 k_h4);
// 96..127: S role (R4 k_statsq2).
__global__ __launch_bounds__(256) void k_dhs(
    const float* __restrict__ Gp0, const float* __restrict__ Gp1,
    const float* __restrict__ g_gru, const float* __restrict__ b_gru,
    float* __restrict__ deterf, unsigned short* __restrict__ deterb,
    unsigned short* __restrict__ deter_allb,
    const unsigned short* __restrict__ pWood, float* __restrict__ hpart,
    const unsigned short* __restrict__ pWobs, const float* __restrict__ E_pre,
    const float* __restrict__ g_oo, const float* __restrict__ b_oo,
    const float* __restrict__ b_obs, const float* __restrict__ noise_po,
    float* __restrict__ out, unsigned short* __restrict__ stochb,
    int* __restrict__ fD, int* __restrict__ fH, int t)
{
    __shared__ __align__(16) char smem[74240];
    unsigned short (*sb)[32 * 512] = reinterpret_cast<unsigned short(*)[32 * 512]>(smem);
    float (*s_out)[66] = reinterpret_cast<float(*)[66]>(smem + 65536);
    float* s_mean = reinterpret_cast<float*>(smem + 65536 + 8448);
    float* s_rstd = s_mean + 32;
    float* gsh = reinterpret_cast<float*>(smem);
    float* red = reinterpret_cast<float*>(smem + 49152);

    int bid = blockIdx.x, tid = threadIdx.x;
    int lane = tid & 63, wv = tid >> 6;
    int c = lane & 15, kb = lane >> 4;

    if (bid < 32) {
        // ---- D role ----
        int r = bid;
        const float* g0 = Gp0 + (long)r * GRUN;
        const float* g1 = Gp1 + (long)r * GRUN;
        float s = 0.f, q = 0.f;
#pragma unroll
        for (int i = 0; i < 12; ++i) {
            int col = tid * 4 + i * 1024;
            f32x4 v = *reinterpret_cast<const f32x4*>(g0 + col);
            v += *reinterpret_cast<const f32x4*>(g1 + col);
            *reinterpret_cast<f32x4*>(gsh + col) = v;
#pragma unroll
            for (int j = 0; j < 4; ++j) { s += v[j]; q += v[j] * v[j]; }
        }
#pragma unroll
        for (int m = 1; m < 64; m <<= 1) { s += __shfl_xor(s, m); q += __shfl_xor(q, m); }
        if (lane == 0) { red[wv] = s; red[4 + wv] = q; }
        __syncthreads();
        float fs = red[0] + red[1] + red[2] + red[3];
        float fq = red[4] + red[5] + red[6] + red[7];
        float mean = fs * (1.f / 12288.f);
        float rstd = rsqrtf(fq * (1.f / 12288.f) - mean * mean + 1e-3f);
        long orow = (long)r * T_ + t;
#pragma unroll
        for (int it = 0; it < 4; ++it) {
            int j = tid * 4 + it * 1024;
            f32x4 rr = *reinterpret_cast<const f32x4*>(gsh + j);
            f32x4 cc = *reinterpret_cast<const f32x4*>(gsh + 4096 + j);
            f32x4 uu = *reinterpret_cast<const f32x4*>(gsh + 8192 + j);
            f32x4 dd = *reinterpret_cast<const f32x4*>(deterf + (long)r * DETER_ + j);
            f32x4 nd; unsigned short db[4];
#pragma unroll
            for (int i = 0; i < 4; ++i) {
                float lr = (rr[i] - mean) * rstd * g_gru[j + i] + b_gru[j + i];
                float lc = (cc[i] - mean) * rstd * g_gru[4096 + j + i] + b_gru[4096 + j + i];
                float lu = (uu[i] - mean) * rstd * g_gru[8192 + j + i] + b_gru[8192 + j + i];
                float reset = sigmoidf_(lr);
                float cand = tanhf_(reset * lc);
                float upd = sigmoidf_(lu - 1.f);
                nd[i] = upd * cand + (1.f - upd) * dd[i];
                db[i] = f2bf(nd[i]);
            }
            *reinterpret_cast<f32x4*>(deterf + (long)r * DETER_ + j) = nd;
            *reinterpret_cast<u16x4*>(deterb + (long)r * DETER_ + j) = *reinterpret_cast<u16x4*>(db);
            *reinterpret_cast<u16x4*>(deter_allb + orow * DETER_ + j) = *reinterpret_cast<u16x4*>(db);
            *reinterpret_cast<f32x4*>(out + orow * 10240 + j) = nd;
        }
        postflag(&fD[t]);
    } else if (bid < 96) {
        // ---- H role: hpart[kq] = deter[:,kq*1024:+1024] @ Wood-slice ----
        int idx = bid - 32;
        int n = idx & 15, kq = idx >> 4;
        const unsigned short* bbase = pWood + ((long)(n * 4 + wv) * 128) * 512 + lane * 8;
        waitflag(&fD[t], 32);
        f32x4 acc0 = {0, 0, 0, 0}, acc1 = {0, 0, 0, 0};
        stage_glds<512>(sb[0], deterb, 4096, (long)kq * 1024);
        stage_glds<512>(sb[1], deterb, 4096, (long)kq * 1024 + 512);
        vmwaitN<8>(); barrier_();
        mfma2<512>(sb[0], c, kb, bbase + (long)(kq * 32) * 512, acc0, acc1);
        vmwaitN<0>(); barrier_();
        mfma2<512>(sb[1], c, kb, bbase + (long)(kq * 32 + 16) * 512, acc0, acc1);
        __syncthreads();
#pragma unroll
        for (int j = 0; j < 4; ++j) {
            s_out[kb * 4 + j][wv * 16 + c] = acc0[j];
            s_out[16 + kb * 4 + j][wv * 16 + c] = acc1[j];
        }
        __syncthreads();
        int row = tid >> 3, c8 = (tid & 7) * 8;
        float* hp = hpart + (long)kq * 32768 + (long)row * 1024 + n * 64 + c8;
#pragma unroll
        for (int i = 0; i < 8; ++i) hp[i] = s_out[row][c8 + i];
        postflag(&fH[t]);
    } else {
        // ---- S role: posterior stats + sample ----
        int s_ = bid - 96;
        waitflag(&fH[t], 64);
        {
            int row = tid >> 3, c0 = (tid & 7) * 128;
            const float* h0 = hpart + (long)row * 1024 + c0;
            const float* ep = E_pre + ((long)row * T_ + t) * 1024 + c0;
            float s = 0.f, q = 0.f;
#pragma unroll 8
            for (int kk = 0; kk < 128; kk += 4) {
                f32x4 v = *reinterpret_cast<const f32x4*>(h0 + kk);
                v += *reinterpret_cast<const f32x4*>(h0 + 32768 + kk);
                v += *reinterpret_cast<const f32x4*>(h0 + 65536 + kk);
                v += *reinterpret_cast<const f32x4*>(h0 + 98304 + kk);
                v += *reinterpret_cast<const f32x4*>(ep + kk);
#pragma unroll
                for (int j2 = 0; j2 < 4; ++j2) { s += v[j2]; q += v[j2] * v[j2]; }
            }
#pragma unroll
            for (int m = 1; m < 8; m <<= 1) { s += __shfl_xor(s, m); q += __shfl_xor(q, m); }
            if ((tid & 7) == 0) {
                float mm = s * (1.f / 1024.f);
                s_mean[row] = mm;
                s_rstd[row] = rsqrtf(q * (1.f / 1024.f) - mm * mm + 1e-3f);
            }
        }
        __syncthreads();
        int part = wv >> 1, nt = wv & 1;
        long ntg = (long)part * 64 + s_ * 2 + nt;
        const unsigned short* bbase = pWobs + ntg * 32 * 512 + lane * 8;
        f32x4 acc0 = {0, 0, 0, 0}, acc1 = {0, 0, 0, 0};
        stage_lnsum(sb[0], hpart, E_pre, t, 0, g_oo, b_oo, s_mean, s_rstd);
        stage_lnsum(sb[1], hpart, E_pre, t, 512, g_oo, b_oo, s_mean, s_rstd);
        lgkmwait_(); barrier_();
        mfma2<512>(sb[0], c, kb, bbase, acc0, acc1);
        mfma2<512>(sb[1], c, kb, bbase + 16 * 512, acc0, acc1);
        __syncthreads();
        float bv = b_obs[ntg * 16 + c];
#pragma unroll
        for (int j = 0; j < 4; ++j) {
            s_out[kb * 4 + j][part * 32 + nt * 16 + c] = acc0[j] + bv;
            s_out[16 + kb * 4 + j][part * 32 + nt * 16 + c] = acc1[j] + bv;
        }
        __syncthreads();
        int r = tid >> 3, j0 = (tid & 7) * 4;
        long orow = (long)r * T_ + t;
#pragma unroll
        for (int i = 0; i < 4; ++i) {
            int j = j0 + i;
            float mean = s_out[r][j];
            float sd = softplusf_(s_out[r][32 + j]) + 0.1f;
            int cg2 = s_ * 32 + j;
            float st = mean + sd * noise_po[orow * 1024 + cg2];
            float* op = out + orow * 10240;
            op[4096 + cg2] = st; op[5120 + cg2] = mean; op[6144 + cg2] = sd;
            stochb[(long)r * 1024 + cg2] = f2bf(st);
        }
    }
}

// ---------------- batched prior (off critical path; R4-verified) ----------------
__global__ __launch_bounds__(256) void k_bstats(
    const unsigned short* __restrict__ Bp, const unsigned short* __restrict__ h_pb,
    const float* __restrict__ bias, const float* __restrict__ noise,
    float* __restrict__ out)
{
    __shared__ __align__(16) unsigned short sb[2][32 * 512];
    __shared__ float s_out[32][66];
    int tid = threadIdx.x;
    int lane = tid & 63, wv = tid >> 6;
    int part = wv >> 1, nt = wv & 1;
    int c = lane & 15, kb = lane >> 4;
    int s_ = blockIdx.x, rowbase = blockIdx.y * 32;
    const unsigned short* A = h_pb + (long)rowbase * 1024;
    long ntg = (long)part * 64 + s_ * 2 + nt;
    const unsigned short* bbase = Bp + ntg * 32 * 512 + lane * 8;
    f32x4 acc0 = {0.f,0.f,0.f,0.f}, acc1 = {0.f,0.f,0.f,0.f};
    stage_glds<512>(sb[0], A, 1024, 0);
    stage_glds<512>(sb[1], A, 1024, 512);
    vmwaitN<8>(); barrier_();
    mfma_rh<512>(sb[0], c, kb, bbase, acc0);
    mfma_rh<512>(sb[0], 16 + c, kb, bbase, acc1);
    vmwaitN<0>(); barrier_();
    mfma_rh<512>(sb[1], c, kb, bbase + 16 * 512, acc0);
    mfma_rh<512>(sb[1], 16 + c, kb, bbase + 16 * 512, acc1);
    __syncthreads();
    float bv = bias[ntg * 16 + c];
#pragma unroll
    for (int j = 0; j < 4; ++j) {
        s_out[kb * 4 + j][part * 32 + nt * 16 + c] = acc0[j] + bv;
        s_out[16 + kb * 4 + j][part * 32 + nt * 16 + c] = acc1[j] + bv;
    }
    __syncthreads();
    int r = tid >> 3, j0 = (tid & 7) * 4;
    long orow = rowbase + r;
#pragma unroll
    for (int i = 0; i < 4; ++i) {
        int j = j0 + i;
        float mean = s_out[r][j];
        float sd = softplusf_(s_out[r][32 + j]) + 0.1f;
        int cg2 = s_ * 32 + j;
        float st = mean + sd * noise[orow * 1024 + cg2];
        float* op = out + orow * 10240;
        op[7168 + cg2] = st; op[8192 + cg2] = mean; op[9216 + cg2] = sd;
    }
}

__global__ __launch_bounds__(256) void k_bfin(const float* __restrict__ hp_raw,
                                              const float* __restrict__ pbh,
                                              const float* __restrict__ g_io,
                                              const float* __restrict__ b_io,
                                              unsigned short* __restrict__ h_pb) {
    int row = blockIdx.x * 8 + ((int)threadIdx.x >> 5);
    int l = threadIdx.x & 31;
    float s = pbh[((long)l * 2048 + row) * 2];
    float q = pbh[((long)l * 2048 + row) * 2 + 1];
#pragma unroll
    for (int m = 16; m; m >>= 1) { s += __shfl_xor(s, m, 32); q += __shfl_xor(q, m, 32); }
    float mn = s * (1.f / 1024.f);
    float rs = rsqrtf(q * (1.f / 1024.f) - mn * mn + 1e-3f);
#pragma unroll
    for (int i = 0; i < 8; ++i) {
        int col = i * 128 + l * 4;
        f32x4 v = *reinterpret_cast<const f32x4*>(hp_raw + (long)row * 1024 + col);
        unsigned short pk[4];
#pragma unroll
        for (int j = 0; j < 4; ++j) {
            float ln = (v[j] - mn) * rs * g_io[col + j] + b_io[col + j];
            pk[j] = f2bf(siluf_(ln));
        }
        *reinterpret_cast<u16x4*>(h_pb + (long)row * 1024 + col) = *reinterpret_cast<u16x4*>(pk);
    }
}

// ---------------- host ----------------

extern "C" void kernel_launch(void* const* d_in, const int* in_sizes, int n_in,
                              void* d_out, int out_size, void* d_ws, size_t ws_size,
                              hipStream_t stream) {
    const float* embed      = (const float*)d_in[0];
    const float* action     = (const float*)d_in[1];
    const float* init_deter = (const float*)d_in[3];
    const float* init_stoch = (const float*)d_in[4];
    const float* noise_pr   = (const float*)d_in[5];
    const float* noise_po   = (const float*)d_in[6];
    const float* W_in       = (const float*)d_in[7];
    const float* g_in       = (const float*)d_in[8];
    const float* b_in       = (const float*)d_in[9];
    const float* W_gru      = (const float*)d_in[10];
    const float* g_gru      = (const float*)d_in[11];
    const float* b_gru      = (const float*)d_in[12];
    const float* W_io       = (const float*)d_in[13];
    const float* g_io       = (const float*)d_in[14];
    const float* b_io       = (const float*)d_in[15];
    const float* W_oo       = (const float*)d_in[16];
    const float* g_oo       = (const float*)d_in[17];
    const float* b_oo       = (const float*)d_in[18];
    const float* W_ims      = (const float*)d_in[19];
    const float* b_ims      = (const float*)d_in[20];
    const float* W_obs      = (const float*)d_in[21];
    const float* b_obs      = (const float*)d_in[22];
    float* out = (float*)d_out;

    char* ws = (char*)d_ws;
    size_t off = 0;
    auto alloc = [&](size_t bytes) {
        size_t r = off;
        off = (off + bytes + 255) & ~(size_t)255;
        return r;
    };
    unsigned short* pWgru  = (unsigned short*)(ws + alloc((size_t)5120 * 12288 * 2));
    unsigned short* pWin_s = (unsigned short*)(ws + alloc((size_t)1024 * 1024 * 2));
    unsigned short* pWin_a = (unsigned short*)(ws + alloc((size_t)128 * 1024 * 2));
    unsigned short* pWio   = (unsigned short*)(ws + alloc((size_t)4096 * 1024 * 2));
    unsigned short* pWood  = (unsigned short*)(ws + alloc((size_t)4096 * 1024 * 2));
    unsigned short* pWooe  = (unsigned short*)(ws + alloc((size_t)1536 * 1024 * 2));
    unsigned short* pWims  = (unsigned short*)(ws + alloc((size_t)1024 * 2048 * 2));
    unsigned short* pWobs  = (unsigned short*)(ws + alloc((size_t)1024 * 2048 * 2));
    unsigned short* act_bf = (unsigned short*)(ws + alloc((size_t)2048 * 128 * 2));
    unsigned short* emb_bf = (unsigned short*)(ws + alloc((size_t)2048 * 1536 * 2));
    float* A_pre  = (float*)(ws + alloc((size_t)2048 * 1024 * 4));
    float* E_pre  = (float*)(ws + alloc((size_t)2048 * 1024 * 4));
    float* x_raw  = (float*)(ws + alloc((size_t)32 * 1024 * 4));
    float* Gp0    = (float*)(ws + alloc((size_t)32 * GRUN * 4));
    float* Gp1    = (float*)(ws + alloc((size_t)32 * GRUN * 4));
    float* deterf = (float*)(ws + alloc((size_t)32 * DETER_ * 4));
    unsigned short* deterb     = (unsigned short*)(ws + alloc((size_t)32 * DETER_ * 2));
    unsigned short* deter_allb = (unsigned short*)(ws + alloc((size_t)2048 * DETER_ * 2));
    unsigned short* stochb = (unsigned short*)(ws + alloc((size_t)32 * 1024 * 2));
    float* hp_raw = (float*)(ws + alloc((size_t)2048 * 1024 * 4));
    unsigned short* h_pb = (unsigned short*)(ws + alloc((size_t)2048 * 1024 * 2));
    float* px  = (float*)(ws + alloc((size_t)32 * 32 * 2 * 4));
    float* pbh = (float*)(ws + alloc((size_t)32 * 2048 * 2 * 4));
    float* hpart = (float*)(ws + alloc((size_t)4 * 32 * 1024 * 4));
    int* flags = (int*)(ws + alloc((size_t)3 * 64 * 4));
    int* fX = flags, *fD = flags + 64, *fH = flags + 128;
    (void)ws_size; (void)out_size; (void)n_in; (void)in_sizes;

    auto packgrid = [](long K, long N) { return (unsigned)((K * N / 8 + 255) / 256); };

    // prep: pack weights
    k_pack<<<packgrid(5120, 12288), 256, 0, stream>>>(W_gru, pWgru, 5120, 12288);
    k_pack<<<packgrid(1024, 1024), 256, 0, stream>>>(W_in, pWin_s, 1024, 1024);
    k_pack<<<packgrid(128, 1024), 256, 0, stream>>>(W_in + (size_t)1024 * 1024, pWin_a, 128, 1024);
    k_pack<<<packgrid(4096, 1024), 256, 0, stream>>>(W_io, pWio, 4096, 1024);
    k_pack<<<packgrid(4096, 1024), 256, 0, stream>>>(W_oo, pWood, 4096, 1024);
    k_pack<<<packgrid(1536, 1024), 256, 0, stream>>>(W_oo + (size_t)4096 * 1024, pWooe, 1536, 1024);
    k_pack<<<packgrid(1024, 2048), 256, 0, stream>>>(W_ims, pWims, 1024, 2048);
    k_pack<<<packgrid(1024, 2048), 256, 0, stream>>>(W_obs, pWobs, 1024, 2048);
    // prep: conversions
    k_conv<<<(2048 * 128 / 4 + 255) / 256, 256, 0, stream>>>(action, act_bf, 2048L * 128);
    k_conv<<<(2048 * 1536 / 4 + 255) / 256, 256, 0, stream>>>(embed, emb_bf, 2048L * 1536);
    k_conv<<<(32 * 1024 / 4 + 255) / 256, 256, 0, stream>>>(init_stoch, stochb, 32L * 1024);
    k_conv<<<(32 * 4096 / 4 + 255) / 256, 256, 0, stream>>>(init_deter, deterb, 32L * 4096);
    k_copy<<<(32 * 4096 / 4 + 255) / 256, 256, 0, stream>>>(init_deter, deterf, 32L * 4096);
    // prep: time-invariant contributions
    k_gemm32<128, 1, 0><<<dim3(32, 64), 256, 0, stream>>>(
        pWin_a, 4, 0, act_bf, 128, nullptr, 0, nullptr, nullptr, nullptr, 0,
        nullptr, 0, A_pre, 1024, nullptr, 0);
    k_gemm32<512, 3, 0><<<dim3(32, 64), 256, 0, stream>>>(
        pWooe, 48, 0, emb_bf, 1536, nullptr, 0, nullptr, nullptr, nullptr, 0,
        nullptr, 0, E_pre, 1024, nullptr, 0);
    // reset flags each launch (ws not re-poisoned between replays)
    k_zeroflags<<<1, 256, 0, stream>>>(flags, 3 * 64);

    for (int t = 0; t < T_; ++t) {
        k_gruxf<<<400, 256, 0, stream>>>(pWin_s, pWgru, stochb, deterb, A_pre,
                                         x_raw, px, g_in, b_in, Gp0, Gp1, fX, t);
        k_dhs<<<128, 256, 0, stream>>>(Gp0, Gp1, g_gru, b_gru, deterf, deterb,
                                       deter_allb, pWood, hpart, pWobs, E_pre,
                                       g_oo, b_oo, b_obs, noise_po, out, stochb,
                                       fD, fH, t);
    }

    // batched prior chain (off critical path)
    k_gemm32<512, 8, 0><<<dim3(32, 64), 256, 0, stream>>>(
        pWio, 128, 0, deter_allb, 4096, nullptr, 0, nullptr, nullptr, nullptr, 0,
        nullptr, 0, hp_raw, 1024, pbh, 2048);
    k_bfin<<<256, 256, 0, stream>>>(hp_raw, pbh, g_io, b_io, h_pb);
    k_bstats<<<dim3(32, 64), 256, 0, stream>>>(pWims, h_pb, b_ims, noise_pr, out);
}

// Round 10
// 7423.151 us; speedup vs baseline: 1.1110x; 1.1110x over previous
//
#include <hip/hip_runtime.h>
#include <hip/hip_bf16.h>

#define T_ 64
#define DETER_ 4096
#define GRUN 12288

typedef __attribute__((ext_vector_type(8))) __bf16 bf16x8;
typedef __attribute__((ext_vector_type(4))) float f32x4;
typedef __attribute__((ext_vector_type(8))) unsigned short u16x8;
typedef __attribute__((ext_vector_type(4))) unsigned short u16x4;

__device__ inline unsigned short f2bf(float f) {
    union { float f; unsigned u; } x; x.f = f;
    unsigned r = x.u + 0x7fffu + ((x.u >> 16) & 1u);
    return (unsigned short)(r >> 16);
}
__device__ inline float sigmoidf_(float v) { return 1.f / (1.f + __expf(-v)); }
__device__ inline float siluf_(float v)    { return v / (1.f + __expf(-v)); }
__device__ inline float softplusf_(float v){ return fmaxf(v, 0.f) + __logf(1.f + __expf(-fabsf(v))); }
__device__ inline float tanhf_(float v)    { return 2.f / (1.f + __expf(-2.f * v)) - 1.f; }

__device__ inline void barrier_() {
    asm volatile("" ::: "memory");
    __builtin_amdgcn_s_barrier();
    asm volatile("" ::: "memory");
}
template <int N> __device__ inline void vmwaitN() {
    asm volatile("s_waitcnt vmcnt(%0)" :: "i"(N) : "memory");
}
__device__ inline void lgkmwait_() {
    asm volatile("s_waitcnt lgkmcnt(0)" ::: "memory");
}

// ---------------- prep kernels ----------------

__global__ __launch_bounds__(256) void k_pack(const float* __restrict__ W,
                                              unsigned short* __restrict__ dst,
                                              int K, int N) {
    long fid = (long)blockIdx.x * 256 + threadIdx.x;
    long nfr = (long)K * N / 8;
    if (fid >= nfr) return;
    int lane = (int)(fid & 63);
    long tile = fid >> 6;
    int ktiles = K >> 5;
    int k_t = (int)(tile % ktiles);
    int n_t = (int)(tile / ktiles);
    int c = lane & 15, kb = lane >> 4;
    int k0 = k_t * 32 + kb * 8;
    int n = n_t * 16 + c;
    unsigned short v[8];
#pragma unroll
    for (int i = 0; i < 8; i++) v[i] = f2bf(W[(long)(k0 + i) * N + n]);
    *reinterpret_cast<u16x8*>(dst + fid * 8) = *reinterpret_cast<u16x8*>(v);
}

__global__ __launch_bounds__(256) void k_conv(const float* __restrict__ s,
                                              unsigned short* __restrict__ d, long n) {
    long i = ((long)blockIdx.x * 256 + threadIdx.x) * 4;
    if (i >= n) return;
    f32x4 v = *reinterpret_cast<const f32x4*>(s + i);
    unsigned short o[4];
#pragma unroll
    for (int k = 0; k < 4; k++) o[k] = f2bf(v[k]);
    *reinterpret_cast<u16x4*>(d + i) = *reinterpret_cast<u16x4*>(o);
}

__global__ __launch_bounds__(256) void k_copy(const float* __restrict__ s,
                                              float* __restrict__ d, long n) {
    long i = ((long)blockIdx.x * 256 + threadIdx.x) * 4;
    if (i >= n) return;
    *reinterpret_cast<f32x4*>(d + i) = *reinterpret_cast<const f32x4*>(s + i);
}

// ---------------- staging helpers (R4-verified) ----------------

template <int CW>
__device__ inline void stage_glds(unsigned short* chunk, const unsigned short* __restrict__ src,
                                  long ld, long k0) {
    constexpr int NI = (32 * CW * 2) / 4096;
    int wv = (int)threadIdx.x >> 6, lane = (int)threadIdx.x & 63;
#pragma unroll
    for (int i = 0; i < NI; ++i) {
        int obase = (wv * NI + i) << 10;
        int o = obase + lane * 16;
        int row = o / (CW * 2);
        int cb = o - row * (CW * 2);
        int gb = cb ^ ((row & 7) << 4);
        const char* ga = (const char*)(src + (long)row * ld + k0) + gb;
        __builtin_amdgcn_global_load_lds(
            (const __attribute__((address_space(1))) void*)ga,
            (__attribute__((address_space(3))) void*)(chunk + (obase >> 1)),
            16, 0, 0);
    }
}

__device__ inline void stage_ln512(unsigned short* chunk, const float* __restrict__ raw,
                                   int ld, int col0,
                                   const float* __restrict__ g, const float* __restrict__ b,
                                   const float* s_mean, const float* s_rstd) {
    int tid = threadIdx.x;
#pragma unroll
    for (int i = 0; i < 8; ++i) {
        int e = tid * 8 + i * 2048;
        int row = e >> 9, col = e & 511;
        float m = s_mean[row], rs = s_rstd[row];
        const float* sp = raw + (long)row * ld + col0 + col;
        unsigned short pk[8];
#pragma unroll
        for (int j = 0; j < 8; ++j) {
            float ln = (sp[j] - m) * rs * g[col0 + col + j] + b[col0 + col + j];
            pk[j] = f2bf(siluf_(ln));
        }
        int dcol = col ^ ((row & 7) << 3);
        *reinterpret_cast<u16x8*>(chunk + row * 512 + dcol) = *reinterpret_cast<u16x8*>(pk);
    }
}

__device__ inline void stage_lnsum(unsigned short* chunk, const float* __restrict__ hpart,
                                   const float* __restrict__ eprep, int t, int col0,
                                   const float* __restrict__ g, const float* __restrict__ b,
                                   const float* s_mean, const float* s_rstd) {
    int tid = threadIdx.x;
#pragma unroll
    for (int i = 0; i < 8; ++i) {
        int e = tid * 8 + i * 2048;
        int row = e >> 9, col = e & 511;
        int k = col0 + col;
        float m = s_mean[row], rs = s_rstd[row];
        const float* h0 = hpart + (long)row * 1024 + k;
        const float* ep = eprep + ((long)row * T_ + t) * 1024 + k;
        unsigned short pk[8];
#pragma unroll
        for (int jj = 0; jj < 8; jj += 4) {
            f32x4 v = *reinterpret_cast<const f32x4*>(h0 + jj);
            v += *reinterpret_cast<const f32x4*>(h0 + 32768 + jj);
            v += *reinterpret_cast<const f32x4*>(h0 + 65536 + jj);
            v += *reinterpret_cast<const f32x4*>(h0 + 98304 + jj);
            v += *reinterpret_cast<const f32x4*>(ep + jj);
#pragma unroll
            for (int j2 = 0; j2 < 4; ++j2) {
                float ln = (v[j2] - m) * rs * g[k + jj + j2] + b[k + jj + j2];
                pk[jj + j2] = f2bf(siluf_(ln));
            }
        }
        int dcol = col ^ ((row & 7) << 3);
        *reinterpret_cast<u16x8*>(chunk + row * 512 + dcol) = *reinterpret_cast<u16x8*>(pk);
    }
}

template <int CW>
__device__ inline void mfma_rh(const unsigned short* chunk, int row, int kb,
                               const unsigned short* __restrict__ bp, f32x4& acc) {
    constexpr int NKT = CW / 32;
    const unsigned short* ap = chunk + row * CW;
    int sw = (row & 7) << 3;
#pragma unroll
    for (int kt = 0; kt < NKT; ++kt) {
        bf16x8 a = *reinterpret_cast<const bf16x8*>(ap + ((kb * 8 + kt * 32) ^ sw));
        bf16x8 b = *reinterpret_cast<const bf16x8*>(bp + (long)kt * 512);
        acc = __builtin_amdgcn_mfma_f32_16x16x32_bf16(a, b, acc, 0, 0, 0);
    }
}

template <int CW>
__device__ inline void mfma2(const unsigned short* chunk, int c, int kb,
                             const unsigned short* __restrict__ bp,
                             f32x4& acc0, f32x4& acc1) {
    constexpr int NKT = CW / 32;
    const unsigned short* ap0 = chunk + c * CW;
    const unsigned short* ap1 = chunk + (16 + c) * CW;
    int sw = (c & 7) << 3;
#pragma unroll
    for (int kt = 0; kt < NKT; ++kt) {
        int off = (kb * 8 + kt * 32) ^ sw;
        bf16x8 b = *reinterpret_cast<const bf16x8*>(bp + (long)kt * 512);
        bf16x8 a0 = *reinterpret_cast<const bf16x8*>(ap0 + off);
        bf16x8 a1 = *reinterpret_cast<const bf16x8*>(ap1 + off);
        acc0 = __builtin_amdgcn_mfma_f32_16x16x32_bf16(a0, b, acc0, 0, 0, 0);
        acc1 = __builtin_amdgcn_mfma_f32_16x16x32_bf16(a1, b, acc1, 0, 0, 0);
    }
}

// ---------------- generic 32-row GEMM (prep / x / prior tail; R4-verified) ----------------
template <int CW, int NG, int NL>
__global__ __launch_bounds__(256) void k_gemm32(
    const unsigned short* __restrict__ Bp, int Ktiles, int ktg0,
    const unsigned short* __restrict__ srcA, long ldA,
    const float* __restrict__ lnraw, int lnld,
    const float* __restrict__ g_ln, const float* __restrict__ b_ln,
    const float* __restrict__ pstats, int nslab_in,
    const float* __restrict__ addin, long addin_ld,
    float* __restrict__ outp, long out_ld,
    float* __restrict__ partials, long prows)
{
    constexpr int NCH = NG + NL;
    constexpr int NI = (32 * CW * 2) / 4096;
    __shared__ __align__(16) unsigned short sb[2][32 * CW];
    __shared__ float s_out[32][34];
    __shared__ float s_mean[32], s_rstd[32];
    int tid = threadIdx.x;
    if (NL > 0) {
        if (tid < 32) {
            float s = 0.f, q = 0.f;
            for (int j = 0; j < nslab_in; ++j) {
                s += pstats[((long)j * 32 + tid) * 2];
                q += pstats[((long)j * 32 + tid) * 2 + 1];
            }
            float m = s * (1.f / 1024.f);
            s_mean[tid] = m;
            s_rstd[tid] = rsqrtf(q * (1.f / 1024.f) - m * m + 1e-3f);
        }
        __syncthreads();
    }
    int rowbase = blockIdx.y * 32;
    const unsigned short* srcAr = srcA + (long)rowbase * ldA;
    int lane = tid & 63, wv = tid >> 6;
    int nt = wv >> 1, rh = wv & 1;
    int c = lane & 15, kb = lane >> 4;
    int mrow = rh * 16 + c;
    long ntg = (long)blockIdx.x * 2 + nt;
    const unsigned short* bbase = Bp + (long)ntg * Ktiles * 512 + lane * 8;
    f32x4 acc = {0.f, 0.f, 0.f, 0.f};
    stage_glds<CW>(sb[0], srcAr, ldA, 0);
    for (int ch = 0; ch < NCH; ++ch) {
        int nx = ch + 1;
        if (nx < NG) stage_glds<CW>(sb[nx & 1], srcAr, ldA, (long)nx * CW);
        else if (nx < NCH) stage_ln512(sb[nx & 1], lnraw, lnld, (nx - NG) * 512,
                                       g_ln, b_ln, s_mean, s_rstd);
        if (ch < NG) { if (nx < NG) vmwaitN<NI>(); else vmwaitN<0>(); }
        if (nx >= NG && nx < NCH) lgkmwait_();
        barrier_();
        int kt0 = (ch < NG) ? (ktg0 + ch * (CW / 32)) : ((ch - NG) * 16);
        mfma_rh<CW>(sb[ch & 1], mrow, kb, bbase + (long)kt0 * 512, acc);
        barrier_();
    }
    __syncthreads();
#pragma unroll
    for (int j = 0; j < 4; ++j) s_out[rh * 16 + kb * 4 + j][nt * 16 + c] = acc[j];
    __syncthreads();
    int orow = tid >> 3, c4 = (tid & 7) * 4;
    long rg = rowbase + orow;
    float v[4]; float s = 0.f, q = 0.f;
#pragma unroll
    for (int i = 0; i < 4; ++i) {
        float x = s_out[orow][c4 + i];
        if (addin) x += addin[rg * addin_ld + blockIdx.x * 32 + c4 + i];
        v[i] = x; s += x; q += x * x;
    }
#pragma unroll
    for (int i = 0; i < 4; ++i) outp[rg * out_ld + blockIdx.x * 32 + c4 + i] = v[i];
    if (partials) {
#pragma unroll
        for (int m = 1; m < 8; m <<= 1) { s += __shfl_xor(s, m); q += __shfl_xor(q, m); }
        if ((tid & 7) == 0) {
            partials[((long)blockIdx.x * prows + rg) * 2] = s;
            partials[((long)blockIdx.x * prows + rg) * 2 + 1] = q;
        }
    }
}

// ---------------- GRU GEMM, K-split 2, SINGLE-BUFFER A + s_out overlay ----------------
// Same math/mapping as R4 k_gru2; LDS 33 KB -> 4 blocks/CU (was 73 KB -> 2).
__global__ __launch_bounds__(256, 4) void k_gru2(
    const unsigned short* __restrict__ Bp,
    const unsigned short* __restrict__ deterb,
    const float* __restrict__ x_raw, const float* __restrict__ px,
    const float* __restrict__ g_in, const float* __restrict__ b_in,
    float* __restrict__ Gp0, float* __restrict__ Gp1)
{
    __shared__ __align__(16) char smem[32768];        // A-tile, overlaid by s_out in epilogue
    unsigned short* sbuf = reinterpret_cast<unsigned short*>(smem);
    float (*s_out)[66] = reinterpret_cast<float(*)[66]>(smem);
    __shared__ float s_mean[32], s_rstd[32];
    int tid = threadIdx.x, lane = tid & 63, wv = tid >> 6;
    int c = lane & 15, kb = lane >> 4;
    long ntg = (long)blockIdx.x * 4 + wv;
    const unsigned short* bbase = Bp + ntg * 160 * 512 + lane * 8;
    f32x4 acc0 = {0,0,0,0}, acc1 = {0,0,0,0};

    if (blockIdx.y == 0) {
        if (tid < 32) {
            float s = 0.f, q = 0.f;
            for (int j = 0; j < 32; ++j) {
                s += px[((long)j * 32 + tid) * 2];
                q += px[((long)j * 32 + tid) * 2 + 1];
            }
            float m = s * (1.f / 1024.f);
            s_mean[tid] = m;
            s_rstd[tid] = rsqrtf(q * (1.f / 1024.f) - m * m + 1e-3f);
        }
        __syncthreads();
        // deter chunks 0..2 (ktiles 32,48,64)
#pragma unroll
        for (int ch = 0; ch < 3; ++ch) {
            stage_glds<512>(sbuf, deterb, 4096, (long)ch * 512);
            vmwaitN<0>(); barrier_();
            mfma2<512>(sbuf, c, kb, bbase + (long)(32 + ch * 16) * 512, acc0, acc1);
            barrier_();
        }
        // x LN chunks (ktiles 0,16)
        stage_ln512(sbuf, x_raw, 1024, 0, g_in, b_in, s_mean, s_rstd);
        lgkmwait_(); barrier_();
        mfma2<512>(sbuf, c, kb, bbase, acc0, acc1);
        barrier_();
        stage_ln512(sbuf, x_raw, 1024, 512, g_in, b_in, s_mean, s_rstd);
        lgkmwait_(); barrier_();
        mfma2<512>(sbuf, c, kb, bbase + (long)16 * 512, acc0, acc1);
    } else {
        // deter chunks 3..7 (offsets 1536..3584, ktiles 80..144)
#pragma unroll
        for (int ch = 0; ch < 5; ++ch) {
            stage_glds<512>(sbuf, deterb, 4096, 1536 + (long)ch * 512);
            vmwaitN<0>(); barrier_();
            mfma2<512>(sbuf, c, kb, bbase + (long)(80 + ch * 16) * 512, acc0, acc1);
            barrier_();
        }
    }
    __syncthreads();
#pragma unroll
    for (int j = 0; j < 4; ++j) {
        s_out[kb * 4 + j][wv * 16 + c] = acc0[j];
        s_out[16 + kb * 4 + j][wv * 16 + c] = acc1[j];
    }
    __syncthreads();
    float* G = (blockIdx.y == 0) ? Gp0 : Gp1;
    int row = tid >> 3, c8 = (tid & 7) * 8;
#pragma unroll
    for (int i = 0; i < 8; ++i)
        G[(long)row * GRUN + blockIdx.x * 64 + c8 + i] = s_out[row][c8 + i];
}

// ---------------- GRU finalize (R4-verified, unchanged) ----------------
__global__ __launch_bounds__(1024) void k_deter2(
    const float* __restrict__ Gp0, const float* __restrict__ Gp1,
    const float* __restrict__ g_gru, const float* __restrict__ b_gru,
    float* __restrict__ deterf, unsigned short* __restrict__ deterb,
    unsigned short* __restrict__ deter_allb, float* __restrict__ out, int t)
{
    __shared__ float gsh[GRUN];
    __shared__ float red[32];
    int r = blockIdx.x, tid = threadIdx.x;
    int lane = tid & 63, wv = tid >> 6;
    const float* a0 = Gp0 + (long)r * GRUN;
    const float* a1 = Gp1 + (long)r * GRUN;
    float s = 0.f, q = 0.f;
#pragma unroll
    for (int i = 0; i < 3; ++i) {
        int col = (tid + i * 1024) * 4;
        f32x4 v = *reinterpret_cast<const f32x4*>(a0 + col);
        v += *reinterpret_cast<const f32x4*>(a1 + col);
        *reinterpret_cast<f32x4*>(gsh + col) = v;
#pragma unroll
        for (int j = 0; j < 4; ++j) { s += v[j]; q += v[j] * v[j]; }
    }
#pragma unroll
    for (int m = 1; m < 64; m <<= 1) { s += __shfl_xor(s, m); q += __shfl_xor(q, m); }
    if (lane == 0) { red[wv] = s; red[16 + wv] = q; }
    __syncthreads();
    float fs = 0.f, fq = 0.f;
#pragma unroll
    for (int i = 0; i < 16; ++i) { fs += red[i]; fq += red[16 + i]; }
    float mean = fs * (1.f / 12288.f);
    float rstd = rsqrtf(fq * (1.f / 12288.f) - mean * mean + 1e-3f);
    long orow = (long)r * T_ + t;
#pragma unroll
    for (int it = 0; it < 2; ++it) {
        int j = tid * 2 + it * 2048;
        float2 rr = *reinterpret_cast<const float2*>(gsh + j);
        float2 cc = *reinterpret_cast<const float2*>(gsh + 4096 + j);
        float2 uu = *reinterpret_cast<const float2*>(gsh + 8192 + j);
        float2 dd = *reinterpret_cast<const float2*>(deterf + (long)r * DETER_ + j);
        float dn[2]; unsigned short db[2];
#pragma unroll
        for (int i = 0; i < 2; ++i) {
            float gv = (i == 0) ? rr.x : rr.y;
            float cv = (i == 0) ? cc.x : cc.y;
            float uv = (i == 0) ? uu.x : uu.y;
            float dv = (i == 0) ? dd.x : dd.y;
            float lr = (gv - mean) * rstd * g_gru[j + i] + b_gru[j + i];
            float lc = (cv - mean) * rstd * g_gru[4096 + j + i] + b_gru[4096 + j + i];
            float lu = (uv - mean) * rstd * g_gru[8192 + j + i] + b_gru[8192 + j + i];
            float reset = sigmoidf_(lr);
            float cand = tanhf_(reset * lc);
            float upd = sigmoidf_(lu - 1.f);
            dn[i] = upd * cand + (1.f - upd) * dv;
            db[i] = f2bf(dn[i]);
        }
        float2 nd; nd.x = dn[0]; nd.y = dn[1];
        *reinterpret_cast<float2*>(deterf + (long)r * DETER_ + j) = nd;
        unsigned pk = (unsigned)db[0] | ((unsigned)db[1] << 16);
        *reinterpret_cast<unsigned*>(deterb + (long)r * DETER_ + j) = pk;
        *reinterpret_cast<unsigned*>(deter_allb + orow * DETER_ + j) = pk;
        *reinterpret_cast<float2*>(out + orow * 10240 + j) = nd;
    }
}

// ---------------- h GEMM, K-split 4, single-buffer + overlay ----------------
__global__ __launch_bounds__(256, 4) void k_h4(
    const unsigned short* __restrict__ Wood,
    const unsigned short* __restrict__ deterb,
    float* __restrict__ hpart)
{
    __shared__ __align__(16) char smem[32768];
    unsigned short* sbuf = reinterpret_cast<unsigned short*>(smem);
    float (*s_out)[66] = reinterpret_cast<float(*)[66]>(smem);
    int tid = threadIdx.x, lane = tid & 63, wv = tid >> 6;
    int c = lane & 15, kb = lane >> 4;
    int n = blockIdx.x, kq = blockIdx.y;
    const unsigned short* bbase = Wood + ((long)(n * 4 + wv) * 128) * 512 + lane * 8;
    f32x4 acc0 = {0,0,0,0}, acc1 = {0,0,0,0};
    stage_glds<512>(sbuf, deterb, 4096, (long)kq * 1024);
    vmwaitN<0>(); barrier_();
    mfma2<512>(sbuf, c, kb, bbase + (long)(kq * 32) * 512, acc0, acc1);
    barrier_();
    stage_glds<512>(sbuf, deterb, 4096, (long)kq * 1024 + 512);
    vmwaitN<0>(); barrier_();
    mfma2<512>(sbuf, c, kb, bbase + (long)(kq * 32 + 16) * 512, acc0, acc1);
    __syncthreads();
#pragma unroll
    for (int j = 0; j < 4; ++j) {
        s_out[kb * 4 + j][wv * 16 + c] = acc0[j];
        s_out[16 + kb * 4 + j][wv * 16 + c] = acc1[j];
    }
    __syncthreads();
    int row = tid >> 3, c8 = (tid & 7) * 8;
    float* hp = hpart + (long)kq * 32768 + (long)row * 1024 + n * 64 + c8;
#pragma unroll
    for (int i = 0; i < 8; ++i) hp[i] = s_out[row][c8 + i];
}

// ---------------- posterior stats + sample, single-buffer + overlay ----------------
__global__ __launch_bounds__(256, 4) void k_statsq2(
    const unsigned short* __restrict__ Bp, const float* __restrict__ hpart,
    const float* __restrict__ E_pre,
    const float* __restrict__ g_oo, const float* __restrict__ b_oo,
    const float* __restrict__ bias,
    const float* __restrict__ noise, float* __restrict__ out,
    unsigned short* __restrict__ stochb, int t)
{
    __shared__ __align__(16) char smem[32768];
    unsigned short* sbuf = reinterpret_cast<unsigned short*>(smem);
    float (*s_out)[66] = reinterpret_cast<float(*)[66]>(smem);
    __shared__ float s_mean[32], s_rstd[32];
    int tid = threadIdx.x, lane = tid & 63, wv = tid >> 6;
    int c = lane & 15, kb = lane >> 4;
    {
        int row = tid >> 3, c0 = (tid & 7) * 128;
        const float* h0 = hpart + (long)row * 1024 + c0;
        const float* ep = E_pre + ((long)row * T_ + t) * 1024 + c0;
        float s = 0.f, q = 0.f;
#pragma unroll 8
        for (int kk = 0; kk < 128; kk += 4) {
            f32x4 v = *reinterpret_cast<const f32x4*>(h0 + kk);
            v += *reinterpret_cast<const f32x4*>(h0 + 32768 + kk);
            v += *reinterpret_cast<const f32x4*>(h0 + 65536 + kk);
            v += *reinterpret_cast<const f32x4*>(h0 + 98304 + kk);
            v += *reinterpret_cast<const f32x4*>(ep + kk);
#pragma unroll
            for (int j2 = 0; j2 < 4; ++j2) { s += v[j2]; q += v[j2] * v[j2]; }
        }
#pragma unroll
        for (int m = 1; m < 8; m <<= 1) { s += __shfl_xor(s, m); q += __shfl_xor(q, m); }
        if ((tid & 7) == 0) {
            float mm = s * (1.f / 1024.f);
            s_mean[row] = mm;
            s_rstd[row] = rsqrtf(q * (1.f / 1024.f) - mm * mm + 1e-3f);
        }
    }
    __syncthreads();
    int part = wv >> 1, nt = wv & 1;
    long ntg = (long)part * 64 + blockIdx.x * 2 + nt;
    const unsigned short* bbase = Bp + ntg * 32 * 512 + lane * 8;
    f32x4 acc0 = {0,0,0,0}, acc1 = {0,0,0,0};
    stage_lnsum(sbuf, hpart, E_pre, t, 0, g_oo, b_oo, s_mean, s_rstd);
    lgkmwait_(); barrier_();
    mfma2<512>(sbuf, c, kb, bbase, acc0, acc1);
    barrier_();
    stage_lnsum(sbuf, hpart, E_pre, t, 512, g_oo, b_oo, s_mean, s_rstd);
    lgkmwait_(); barrier_();
    mfma2<512>(sbuf, c, kb, bbase + 16 * 512, acc0, acc1);
    __syncthreads();
    float bv = bias[ntg * 16 + c];
#pragma unroll
    for (int j = 0; j < 4; ++j) {
        s_out[kb * 4 + j][part * 32 + nt * 16 + c] = acc0[j] + bv;
        s_out[16 + kb * 4 + j][part * 32 + nt * 16 + c] = acc1[j] + bv;
    }
    __syncthreads();
    int r = tid >> 3, j0 = (tid & 7) * 4;
    long orow = (long)r * T_ + t;
#pragma unroll
    for (int i = 0; i < 4; ++i) {
        int j = j0 + i;
        float mean = s_out[r][j];
        float sd = softplusf_(s_out[r][32 + j]) + 0.1f;
        int cg2 = blockIdx.x * 32 + j;
        float st = mean + sd * noise[orow * 1024 + cg2];
        float* op = out + orow * 10240;
        op[4096 + cg2] = st; op[5120 + cg2] = mean; op[6144 + cg2] = sd;
        stochb[(long)r * 1024 + cg2] = f2bf(st);
    }
}

// ---------------- batched prior (off critical path; R4-verified) ----------------
__global__ __launch_bounds__(256) void k_bstats(
    const unsigned short* __restrict__ Bp, const unsigned short* __restrict__ h_pb,
    const float* __restrict__ bias, const float* __restrict__ noise,
    float* __restrict__ out)
{
    __shared__ __align__(16) unsigned short sb[2][32 * 512];
    __shared__ float s_out[32][66];
    int tid = threadIdx.x;
    int lane = tid & 63, wv = tid >> 6;
    int part = wv >> 1, nt = wv & 1;
    int c = lane & 15, kb = lane >> 4;
    int s_ = blockIdx.x, rowbase = blockIdx.y * 32;
    const unsigned short* A = h_pb + (long)rowbase * 1024;
    long ntg = (long)part * 64 + s_ * 2 + nt;
    const unsigned short* bbase = Bp + ntg * 32 * 512 + lane * 8;
    f32x4 acc0 = {0.f,0.f,0.f,0.f}, acc1 = {0.f,0.f,0.f,0.f};
    stage_glds<512>(sb[0], A, 1024, 0);
    stage_glds<512>(sb[1], A, 1024, 512);
    vmwaitN<8>(); barrier_();
    mfma_rh<512>(sb[0], c, kb, bbase, acc0);
    mfma_rh<512>(sb[0], 16 + c, kb, bbase, acc1);
    vmwaitN<0>(); barrier_();
    mfma_rh<512>(sb[1], c, kb, bbase + 16 * 512, acc0);
    mfma_rh<512>(sb[1], 16 + c, kb, bbase + 16 * 512, acc1);
    __syncthreads();
    float bv = bias[ntg * 16 + c];
#pragma unroll
    for (int j = 0; j < 4; ++j) {
        s_out[kb * 4 + j][part * 32 + nt * 16 + c] = acc0[j] + bv;
        s_out[16 + kb * 4 + j][part * 32 + nt * 16 + c] = acc1[j] + bv;
    }
    __syncthreads();
    int r = tid >> 3, j0 = (tid & 7) * 4;
    long orow = rowbase + r;
#pragma unroll
    for (int i = 0; i < 4; ++i) {
        int j = j0 + i;
        float mean = s_out[r][j];
        float sd = softplusf_(s_out[r][32 + j]) + 0.1f;
        int cg2 = s_ * 32 + j;
        float st = mean + sd * noise[orow * 1024 + cg2];
        float* op = out + orow * 10240;
        op[7168 + cg2] = st; op[8192 + cg2] = mean; op[9216 + cg2] = sd;
    }
}

__global__ __launch_bounds__(256) void k_bfin(const float* __restrict__ hp_raw,
                                              const float* __restrict__ pbh,
                                              const float* __restrict__ g_io,
                                              const float* __restrict__ b_io,
                                              unsigned short* __restrict__ h_pb) {
    int row = blockIdx.x * 8 + ((int)threadIdx.x >> 5);
    int l = threadIdx.x & 31;
    float s = pbh[((long)l * 2048 + row) * 2];
    float q = pbh[((long)l * 2048 + row) * 2 + 1];
#pragma unroll
    for (int m = 16; m; m >>= 1) { s += __shfl_xor(s, m, 32); q += __shfl_xor(q, m, 32); }
    float mn = s * (1.f / 1024.f);
    float rs = rsqrtf(q * (1.f / 1024.f) - mn * mn + 1e-3f);
#pragma unroll
    for (int i = 0; i < 8; ++i) {
        int col = i * 128 + l * 4;
        f32x4 v = *reinterpret_cast<const f32x4*>(hp_raw + (long)row * 1024 + col);
        unsigned short pk[4];
#pragma unroll
        for (int j = 0; j < 4; ++j) {
            float ln = (v[j] - mn) * rs * g_io[col + j] + b_io[col + j];
            pk[j] = f2bf(siluf_(ln));
        }
        *reinterpret_cast<u16x4*>(h_pb + (long)row * 1024 + col) = *reinterpret_cast<u16x4*>(pk);
    }
}

// ---------------- host ----------------

extern "C" void kernel_launch(void* const* d_in, const int* in_sizes, int n_in,
                              void* d_out, int out_size, void* d_ws, size_t ws_size,
                              hipStream_t stream) {
    const float* embed      = (const float*)d_in[0];
    const float* action     = (const float*)d_in[1];
    const float* init_deter = (const float*)d_in[3];
    const float* init_stoch = (const float*)d_in[4];
    const float* noise_pr   = (const float*)d_in[5];
    const float* noise_po   = (const float*)d_in[6];
    const float* W_in       = (const float*)d_in[7];
    const float* g_in       = (const float*)d_in[8];
    const float* b_in       = (const float*)d_in[9];
    const float* W_gru      = (const float*)d_in[10];
    const float* g_gru      = (const float*)d_in[11];
    const float* b_gru      = (const float*)d_in[12];
    const float* W_io       = (const float*)d_in[13];
    const float* g_io       = (const float*)d_in[14];
    const float* b_io       = (const float*)d_in[15];
    const float* W_oo       = (const float*)d_in[16];
    const float* g_oo       = (const float*)d_in[17];
    const float* b_oo       = (const float*)d_in[18];
    const float* W_ims      = (const float*)d_in[19];
    const float* b_ims      = (const float*)d_in[20];
    const float* W_obs      = (const float*)d_in[21];
    const float* b_obs      = (const float*)d_in[22];
    float* out = (float*)d_out;

    char* ws = (char*)d_ws;
    size_t off = 0;
    auto alloc = [&](size_t bytes) {
        size_t r = off;
        off = (off + bytes + 255) & ~(size_t)255;
        return r;
    };
    unsigned short* pWgru  = (unsigned short*)(ws + alloc((size_t)5120 * 12288 * 2));
    unsigned short* pWin_s = (unsigned short*)(ws + alloc((size_t)1024 * 1024 * 2));
    unsigned short* pWin_a = (unsigned short*)(ws + alloc((size_t)128 * 1024 * 2));
    unsigned short* pWio   = (unsigned short*)(ws + alloc((size_t)4096 * 1024 * 2));
    unsigned short* pWood  = (unsigned short*)(ws + alloc((size_t)4096 * 1024 * 2));
    unsigned short* pWooe  = (unsigned short*)(ws + alloc((size_t)1536 * 1024 * 2));
    unsigned short* pWims  = (unsigned short*)(ws + alloc((size_t)1024 * 2048 * 2));
    unsigned short* pWobs  = (unsigned short*)(ws + alloc((size_t)1024 * 2048 * 2));
    unsigned short* act_bf = (unsigned short*)(ws + alloc((size_t)2048 * 128 * 2));
    unsigned short* emb_bf = (unsigned short*)(ws + alloc((size_t)2048 * 1536 * 2));
    float* A_pre  = (float*)(ws + alloc((size_t)2048 * 1024 * 4));
    float* E_pre  = (float*)(ws + alloc((size_t)2048 * 1024 * 4));
    float* x_raw  = (float*)(ws + alloc((size_t)32 * 1024 * 4));
    float* Gp0    = (float*)(ws + alloc((size_t)32 * GRUN * 4));
    float* Gp1    = (float*)(ws + alloc((size_t)32 * GRUN * 4));
    float* deterf = (float*)(ws + alloc((size_t)32 * DETER_ * 4));
    unsigned short* deterb     = (unsigned short*)(ws + alloc((size_t)32 * DETER_ * 2));
    unsigned short* deter_allb = (unsigned short*)(ws + alloc((size_t)2048 * DETER_ * 2));
    unsigned short* stochb = (unsigned short*)(ws + alloc((size_t)32 * 1024 * 2));
    float* hp_raw = (float*)(ws + alloc((size_t)2048 * 1024 * 4));
    unsigned short* h_pb = (unsigned short*)(ws + alloc((size_t)2048 * 1024 * 2));
    float* px  = (float*)(ws + alloc((size_t)32 * 32 * 2 * 4));
    float* pbh = (float*)(ws + alloc((size_t)32 * 2048 * 2 * 4));
    float* hpart = (float*)(ws + alloc((size_t)4 * 32 * 1024 * 4));
    (void)ws_size; (void)out_size; (void)n_in; (void)in_sizes;

    auto packgrid = [](long K, long N) { return (unsigned)((K * N / 8 + 255) / 256); };

    // prep: pack weights
    k_pack<<<packgrid(5120, 12288), 256, 0, stream>>>(W_gru, pWgru, 5120, 12288);
    k_pack<<<packgrid(1024, 1024), 256, 0, stream>>>(W_in, pWin_s, 1024, 1024);
    k_pack<<<packgrid(128, 1024), 256, 0, stream>>>(W_in + (size_t)1024 * 1024, pWin_a, 128, 1024);
    k_pack<<<packgrid(4096, 1024), 256, 0, stream>>>(W_io, pWio, 4096, 1024);
    k_pack<<<packgrid(4096, 1024), 256, 0, stream>>>(W_oo, pWood, 4096, 1024);
    k_pack<<<packgrid(1536, 1024), 256, 0, stream>>>(W_oo + (size_t)4096 * 1024, pWooe, 1536, 1024);
    k_pack<<<packgrid(1024, 2048), 256, 0, stream>>>(W_ims, pWims, 1024, 2048);
    k_pack<<<packgrid(1024, 2048), 256, 0, stream>>>(W_obs, pWobs, 1024, 2048);
    // prep: conversions
    k_conv<<<(2048 * 128 / 4 + 255) / 256, 256, 0, stream>>>(action, act_bf, 2048L * 128);
    k_conv<<<(2048 * 1536 / 4 + 255) / 256, 256, 0, stream>>>(embed, emb_bf, 2048L * 1536);
    k_conv<<<(32 * 1024 / 4 + 255) / 256, 256, 0, stream>>>(init_stoch, stochb, 32L * 1024);
    k_conv<<<(32 * 4096 / 4 + 255) / 256, 256, 0, stream>>>(init_deter, deterb, 32L * 4096);
    k_copy<<<(32 * 4096 / 4 + 255) / 256, 256, 0, stream>>>(init_deter, deterf, 32L * 4096);
    // prep: time-invariant contributions  A_pre = act@Win_a ; E_pre = emb@Wooe
    k_gemm32<128, 1, 0><<<dim3(32, 64), 256, 0, stream>>>(
        pWin_a, 4, 0, act_bf, 128, nullptr, 0, nullptr, nullptr, nullptr, 0,
        nullptr, 0, A_pre, 1024, nullptr, 0);
    k_gemm32<512, 3, 0><<<dim3(32, 64), 256, 0, stream>>>(
        pWooe, 48, 0, emb_bf, 1536, nullptr, 0, nullptr, nullptr, nullptr, 0,
        nullptr, 0, E_pre, 1024, nullptr, 0);

    for (int t = 0; t < T_; ++t) {
        // x_raw = stoch@Win_s + A_pre[t]
        k_gemm32<512, 2, 0><<<dim3(32, 1), 256, 0, stream>>>(
            pWin_s, 32, 0, stochb, 1024, nullptr, 0, nullptr, nullptr, nullptr, 0,
            A_pre + (size_t)t * 1024, (long)T_ * 1024, x_raw, 1024, px, 32);
        // Gp[khalf] = partial [silu(LN(x)) | deter] @ Wgru
        k_gru2<<<dim3(192, 2), 256, 0, stream>>>(pWgru, deterb, x_raw, px, g_in, b_in,
                                                 Gp0, Gp1);
        // sum halves, LN, gates -> deter
        k_deter2<<<32, 1024, 0, stream>>>(Gp0, Gp1, g_gru, b_gru, deterf, deterb,
                                          deter_allb, out, t);
        // hpart[kq] = deter-slice @ Wood-slice
        k_h4<<<dim3(16, 4), 256, 0, stream>>>(pWood, deterb, hpart);
        // posterior stats + sample
        k_statsq2<<<32, 256, 0, stream>>>(pWobs, hpart, E_pre, g_oo, b_oo, b_obs,
                                          noise_po, out, stochb, t);
    }

    // batched prior chain (off critical path)
    k_gemm32<512, 8, 0><<<dim3(32, 64), 256, 0, stream>>>(
        pWio, 128, 0, deter_allb, 4096, nullptr, 0, nullptr, nullptr, nullptr, 0,
        nullptr, 0, hp_raw, 1024, pbh, 2048);
    k_bfin<<<256, 256, 0, stream>>>(hp_raw, pbh, g_io, b_io, h_pb);
    k_bstats<<<dim3(32, 64), 256, 0, stream>>>(pWims, h_pb, b_ims, noise_pr, out);
}

// Round 11
// 5980.466 us; speedup vs baseline: 1.3790x; 1.2412x over previous
//
#include <hip/hip_runtime.h>
#include <hip/hip_bf16.h>

#define T_ 64
#define DETER_ 4096
#define GRUN 12288

typedef __attribute__((ext_vector_type(8))) __bf16 bf16x8;
typedef __attribute__((ext_vector_type(4))) float f32x4;
typedef __attribute__((ext_vector_type(8))) unsigned short u16x8;
typedef __attribute__((ext_vector_type(4))) unsigned short u16x4;

__device__ inline unsigned short f2bf(float f) {
    union { float f; unsigned u; } x; x.f = f;
    unsigned r = x.u + 0x7fffu + ((x.u >> 16) & 1u);
    return (unsigned short)(r >> 16);
}
__device__ inline float sigmoidf_(float v) { return 1.f / (1.f + __expf(-v)); }
__device__ inline float siluf_(float v)    { return v / (1.f + __expf(-v)); }
__device__ inline float softplusf_(float v){ return fmaxf(v, 0.f) + __logf(1.f + __expf(-fabsf(v))); }
__device__ inline float tanhf_(float v)    { return 2.f / (1.f + __expf(-2.f * v)) - 1.f; }

__device__ inline void barrier_() {
    asm volatile("" ::: "memory");
    __builtin_amdgcn_s_barrier();
    asm volatile("" ::: "memory");
}
template <int N> __device__ inline void vmwaitN() {
    asm volatile("s_waitcnt vmcnt(%0)" :: "i"(N) : "memory");
}
__device__ inline void lgkmwait_() {
    asm volatile("s_waitcnt lgkmcnt(0)" ::: "memory");
}

// ---------------- prep kernels ----------------

__global__ __launch_bounds__(256) void k_pack(const float* __restrict__ W,
                                              unsigned short* __restrict__ dst,
                                              int K, int N) {
    long fid = (long)blockIdx.x * 256 + threadIdx.x;
    long nfr = (long)K * N / 8;
    if (fid >= nfr) return;
    int lane = (int)(fid & 63);
    long tile = fid >> 6;
    int ktiles = K >> 5;
    int k_t = (int)(tile % ktiles);
    int n_t = (int)(tile / ktiles);
    int c = lane & 15, kb = lane >> 4;
    int k0 = k_t * 32 + kb * 8;
    int n = n_t * 16 + c;
    unsigned short v[8];
#pragma unroll
    for (int i = 0; i < 8; i++) v[i] = f2bf(W[(long)(k0 + i) * N + n]);
    *reinterpret_cast<u16x8*>(dst + fid * 8) = *reinterpret_cast<u16x8*>(v);
}

__global__ __launch_bounds__(256) void k_conv(const float* __restrict__ s,
                                              unsigned short* __restrict__ d, long n) {
    long i = ((long)blockIdx.x * 256 + threadIdx.x) * 4;
    if (i >= n) return;
    f32x4 v = *reinterpret_cast<const f32x4*>(s + i);
    unsigned short o[4];
#pragma unroll
    for (int k = 0; k < 4; k++) o[k] = f2bf(v[k]);
    *reinterpret_cast<u16x4*>(d + i) = *reinterpret_cast<u16x4*>(o);
}

__global__ __launch_bounds__(256) void k_copy(const float* __restrict__ s,
                                              float* __restrict__ d, long n) {
    long i = ((long)blockIdx.x * 256 + threadIdx.x) * 4;
    if (i >= n) return;
    *reinterpret_cast<f32x4*>(d + i) = *reinterpret_cast<const f32x4*>(s + i);
}

// ---------------- staging helpers ----------------

template <int CW>
__device__ inline void stage_glds(unsigned short* chunk, const unsigned short* __restrict__ src,
                                  long ld, long k0) {
    constexpr int NI = (32 * CW * 2) / 4096;
    int wv = (int)threadIdx.x >> 6, lane = (int)threadIdx.x & 63;
#pragma unroll
    for (int i = 0; i < NI; ++i) {
        int obase = (wv * NI + i) << 10;
        int o = obase + lane * 16;
        int row = o / (CW * 2);
        int cb = o - row * (CW * 2);
        int gb = cb ^ ((row & 7) << 4);
        const char* ga = (const char*)(src + (long)row * ld + k0) + gb;
        __builtin_amdgcn_global_load_lds(
            (const __attribute__((address_space(1))) void*)ga,
            (__attribute__((address_space(3))) void*)(chunk + (obase >> 1)),
            16, 0, 0);
    }
}

__device__ inline void stage_ln512(unsigned short* chunk, const float* __restrict__ raw,
                                   int ld, int col0,
                                   const float* __restrict__ g, const float* __restrict__ b,
                                   const float* s_mean, const float* s_rstd) {
    int tid = threadIdx.x;
#pragma unroll
    for (int i = 0; i < 8; ++i) {
        int e = tid * 8 + i * 2048;
        int row = e >> 9, col = e & 511;
        float m = s_mean[row], rs = s_rstd[row];
        const float* sp = raw + (long)row * ld + col0 + col;
        unsigned short pk[8];
#pragma unroll
        for (int j = 0; j < 8; ++j) {
            float ln = (sp[j] - m) * rs * g[col0 + col + j] + b[col0 + col + j];
            pk[j] = f2bf(siluf_(ln));
        }
        int dcol = col ^ ((row & 7) << 3);
        *reinterpret_cast<u16x8*>(chunk + row * 512 + dcol) = *reinterpret_cast<u16x8*>(pk);
    }
}

// CW=256 LN staging (32 rows x 256 cols)
__device__ inline void stage_ln256(unsigned short* chunk, const float* __restrict__ raw,
                                   int ld, int col0,
                                   const float* __restrict__ g, const float* __restrict__ b,
                                   const float* s_mean, const float* s_rstd) {
    int tid = threadIdx.x;
#pragma unroll
    for (int i = 0; i < 4; ++i) {
        int e = tid * 8 + i * 2048;
        int row = e >> 8, col = e & 255;
        float m = s_mean[row], rs = s_rstd[row];
        const float* sp = raw + (long)row * ld + col0 + col;
        unsigned short pk[8];
#pragma unroll
        for (int j = 0; j < 8; ++j) {
            float ln = (sp[j] - m) * rs * g[col0 + col + j] + b[col0 + col + j];
            pk[j] = f2bf(siluf_(ln));
        }
        int dcol = col ^ ((row & 7) << 3);
        *reinterpret_cast<u16x8*>(chunk + row * 256 + dcol) = *reinterpret_cast<u16x8*>(pk);
    }
}

__device__ inline void stage_lnsum(unsigned short* chunk, const float* __restrict__ hpart,
                                   const float* __restrict__ eprep, int t, int col0,
                                   const float* __restrict__ g, const float* __restrict__ b,
                                   const float* s_mean, const float* s_rstd) {
    int tid = threadIdx.x;
#pragma unroll
    for (int i = 0; i < 8; ++i) {
        int e = tid * 8 + i * 2048;
        int row = e >> 9, col = e & 511;
        int k = col0 + col;
        float m = s_mean[row], rs = s_rstd[row];
        const float* h0 = hpart + (long)row * 1024 + k;
        const float* ep = eprep + ((long)row * T_ + t) * 1024 + k;
        unsigned short pk[8];
#pragma unroll
        for (int jj = 0; jj < 8; jj += 4) {
            f32x4 v = *reinterpret_cast<const f32x4*>(h0 + jj);
            v += *reinterpret_cast<const f32x4*>(h0 + 32768 + jj);
            v += *reinterpret_cast<const f32x4*>(h0 + 65536 + jj);
            v += *reinterpret_cast<const f32x4*>(h0 + 98304 + jj);
            v += *reinterpret_cast<const f32x4*>(ep + jj);
#pragma unroll
            for (int j2 = 0; j2 < 4; ++j2) {
                float ln = (v[j2] - m) * rs * g[k + jj + j2] + b[k + jj + j2];
                pk[jj + j2] = f2bf(siluf_(ln));
            }
        }
        int dcol = col ^ ((row & 7) << 3);
        *reinterpret_cast<u16x8*>(chunk + row * 512 + dcol) = *reinterpret_cast<u16x8*>(pk);
    }
}

template <int CW>
__device__ inline void mfma_rh(const unsigned short* chunk, int row, int kb,
                               const unsigned short* __restrict__ bp, f32x4& acc) {
    constexpr int NKT = CW / 32;
    const unsigned short* ap = chunk + row * CW;
    int sw = (row & 7) << 3;
#pragma unroll
    for (int kt = 0; kt < NKT; ++kt) {
        bf16x8 a = *reinterpret_cast<const bf16x8*>(ap + ((kb * 8 + kt * 32) ^ sw));
        bf16x8 b = *reinterpret_cast<const bf16x8*>(bp + (long)kt * 512);
        acc = __builtin_amdgcn_mfma_f32_16x16x32_bf16(a, b, acc, 0, 0, 0);
    }
}

template <int CW>
__device__ inline void mfma2(const unsigned short* chunk, int c, int kb,
                             const unsigned short* __restrict__ bp,
                             f32x4& acc0, f32x4& acc1) {
    constexpr int NKT = CW / 32;
    const unsigned short* ap0 = chunk + c * CW;
    const unsigned short* ap1 = chunk + (16 + c) * CW;
    int sw = (c & 7) << 3;
#pragma unroll
    for (int kt = 0; kt < NKT; ++kt) {
        int off = (kb * 8 + kt * 32) ^ sw;
        bf16x8 b = *reinterpret_cast<const bf16x8*>(bp + (long)kt * 512);
        bf16x8 a0 = *reinterpret_cast<const bf16x8*>(ap0 + off);
        bf16x8 a1 = *reinterpret_cast<const bf16x8*>(ap1 + off);
        acc0 = __builtin_amdgcn_mfma_f32_16x16x32_bf16(a0, b, acc0, 0, 0, 0);
        acc1 = __builtin_amdgcn_mfma_f32_16x16x32_bf16(a1, b, acc1, 0, 0, 0);
    }
}

// ---------------- generic 32-row GEMM (prep / x / prior tail; R4-verified) ----------------
template <int CW, int NG, int NL>
__global__ __launch_bounds__(256) void k_gemm32(
    const unsigned short* __restrict__ Bp, int Ktiles, int ktg0,
    const unsigned short* __restrict__ srcA, long ldA,
    const float* __restrict__ lnraw, int lnld,
    const float* __restrict__ g_ln, const float* __restrict__ b_ln,
    const float* __restrict__ pstats, int nslab_in,
    const float* __restrict__ addin, long addin_ld,
    float* __restrict__ outp, long out_ld,
    float* __restrict__ partials, long prows)
{
    constexpr int NCH = NG + NL;
    constexpr int NI = (32 * CW * 2) / 4096;
    __shared__ __align__(16) unsigned short sb[2][32 * CW];
    __shared__ float s_out[32][34];
    __shared__ float s_mean[32], s_rstd[32];
    int tid = threadIdx.x;
    if (NL > 0) {
        if (tid < 32) {
            float s = 0.f, q = 0.f;
            for (int j = 0; j < nslab_in; ++j) {
                s += pstats[((long)j * 32 + tid) * 2];
                q += pstats[((long)j * 32 + tid) * 2 + 1];
            }
            float m = s * (1.f / 1024.f);
            s_mean[tid] = m;
            s_rstd[tid] = rsqrtf(q * (1.f / 1024.f) - m * m + 1e-3f);
        }
        __syncthreads();
    }
    int rowbase = blockIdx.y * 32;
    const unsigned short* srcAr = srcA + (long)rowbase * ldA;
    int lane = tid & 63, wv = tid >> 6;
    int nt = wv >> 1, rh = wv & 1;
    int c = lane & 15, kb = lane >> 4;
    int mrow = rh * 16 + c;
    long ntg = (long)blockIdx.x * 2 + nt;
    const unsigned short* bbase = Bp + (long)ntg * Ktiles * 512 + lane * 8;
    f32x4 acc = {0.f, 0.f, 0.f, 0.f};
    stage_glds<CW>(sb[0], srcAr, ldA, 0);
    for (int ch = 0; ch < NCH; ++ch) {
        int nx = ch + 1;
        if (nx < NG) stage_glds<CW>(sb[nx & 1], srcAr, ldA, (long)nx * CW);
        else if (nx < NCH) stage_ln512(sb[nx & 1], lnraw, lnld, (nx - NG) * 512,
                                       g_ln, b_ln, s_mean, s_rstd);
        if (ch < NG) { if (nx < NG) vmwaitN<NI>(); else vmwaitN<0>(); }
        if (nx >= NG && nx < NCH) lgkmwait_();
        barrier_();
        int kt0 = (ch < NG) ? (ktg0 + ch * (CW / 32)) : ((ch - NG) * 16);
        mfma_rh<CW>(sb[ch & 1], mrow, kb, bbase + (long)kt0 * 512, acc);
        barrier_();
    }
    __syncthreads();
#pragma unroll
    for (int j = 0; j < 4; ++j) s_out[rh * 16 + kb * 4 + j][nt * 16 + c] = acc[j];
    __syncthreads();
    int orow = tid >> 3, c4 = (tid & 7) * 4;
    long rg = rowbase + orow;
    float v[4]; float s = 0.f, q = 0.f;
#pragma unroll
    for (int i = 0; i < 4; ++i) {
        float x = s_out[orow][c4 + i];
        if (addin) x += addin[rg * addin_ld + blockIdx.x * 32 + c4 + i];
        v[i] = x; s += x; q += x * x;
    }
#pragma unroll
    for (int i = 0; i < 4; ++i) outp[rg * out_ld + blockIdx.x * 32 + c4 + i] = v[i];
    if (partials) {
#pragma unroll
        for (int m = 1; m < 8; m <<= 1) { s += __shfl_xor(s, m); q += __shfl_xor(q, m); }
        if ((tid & 7) == 0) {
            partials[((long)blockIdx.x * prows + rg) * 2] = s;
            partials[((long)blockIdx.x * prows + rg) * 2 + 1] = q;
        }
    }
}

// ---------------- GRU GEMM: K-split 4, CW=256, double-buffered, inline B ----------------
// grid (192, 4). kq0: x (4 LN chunks, ktiles 0..31). kq1: deter 0..1279 (ktiles 32..71).
// kq2: deter 1280..2559 (ktiles 72..111). kq3: deter 2560..4095 (ktiles 112..159).
// Gp layout: [4][32][GRUN]. LDS ~41 KB -> 3 blocks/CU; 768 blocks -> ~12 waves/CU.
__global__ __launch_bounds__(256, 3) void k_gru4(
    const unsigned short* __restrict__ Bp,
    const unsigned short* __restrict__ deterb,
    const float* __restrict__ x_raw, const float* __restrict__ px,
    const float* __restrict__ g_in, const float* __restrict__ b_in,
    float* __restrict__ Gp)
{
    __shared__ __align__(16) unsigned short sb[2][32 * 256];
    __shared__ float s_out[32][66];
    __shared__ float s_mean[32], s_rstd[32];
    int tid = threadIdx.x, lane = tid & 63, wv = tid >> 6;
    int c = lane & 15, kb = lane >> 4;
    int kq = blockIdx.y;
    long ntg = (long)blockIdx.x * 4 + wv;
    const unsigned short* bb = Bp + ntg * 160 * 512 + lane * 8;
    f32x4 acc0 = {0, 0, 0, 0}, acc1 = {0, 0, 0, 0};

    if (kq == 0) {
        if (tid < 32) {
            float s = 0.f, q = 0.f;
            for (int j = 0; j < 32; ++j) {
                s += px[((long)j * 32 + tid) * 2];
                q += px[((long)j * 32 + tid) * 2 + 1];
            }
            float m = s * (1.f / 1024.f);
            s_mean[tid] = m;
            s_rstd[tid] = rsqrtf(q * (1.f / 1024.f) - m * m + 1e-3f);
        }
        __syncthreads();
        stage_ln256(sb[0], x_raw, 1024, 0, g_in, b_in, s_mean, s_rstd);
        stage_ln256(sb[1], x_raw, 1024, 256, g_in, b_in, s_mean, s_rstd);
#pragma unroll
        for (int ch = 0; ch < 4; ++ch) {
            lgkmwait_(); barrier_();
            mfma2<256>(sb[ch & 1], c, kb, bb + (long)(8 * ch) * 512, acc0, acc1);
            barrier_();
            if (ch + 2 < 4)
                stage_ln256(sb[ch & 1], x_raw, 1024, 256 * (ch + 2), g_in, b_in,
                            s_mean, s_rstd);
        }
    } else {
        int nch = (kq == 3) ? 6 : 5;
        long o0 = (kq == 1) ? 0 : (kq == 2 ? 1280 : 2560);
        int kt0 = (kq == 1) ? 32 : (kq == 2 ? 72 : 112);
        stage_glds<256>(sb[0], deterb, 4096, o0);
        stage_glds<256>(sb[1], deterb, 4096, o0 + 256);
        for (int ch = 0; ch < nch; ++ch) {
            // vmcnt ledger: entering ch, outstanding glds = [s_ch:4, s_{ch+1}:4]
            if (ch < nch - 1) vmwaitN<4>(); else vmwaitN<0>();
            barrier_();
            mfma2<256>(sb[ch & 1], c, kb, bb + (long)(kt0 + 8 * ch) * 512, acc0, acc1);
            barrier_();
            if (ch + 2 < nch)
                stage_glds<256>(sb[ch & 1], deterb, 4096, o0 + 256 * (ch + 2));
        }
    }
    __syncthreads();
#pragma unroll
    for (int j = 0; j < 4; ++j) {
        s_out[kb * 4 + j][wv * 16 + c] = acc0[j];
        s_out[16 + kb * 4 + j][wv * 16 + c] = acc1[j];
    }
    __syncthreads();
    int row = tid >> 3, c8 = (tid & 7) * 8;
    float* G = Gp + (long)kq * 32 * GRUN + (long)row * GRUN + blockIdx.x * 64 + c8;
#pragma unroll
    for (int i = 0; i < 8; ++i) G[i] = s_out[row][c8 + i];
}

// ---------------- GRU finalize: sum 4 K-partials, LN on sum, gates (R8-verified) ----------------
__global__ __launch_bounds__(1024) void k_deter4(
    const float* __restrict__ Gp,
    const float* __restrict__ g_gru, const float* __restrict__ b_gru,
    float* __restrict__ deterf, unsigned short* __restrict__ deterb,
    unsigned short* __restrict__ deter_allb, float* __restrict__ out, int t)
{
    __shared__ float gsh[GRUN];
    __shared__ float red[32];
    int r = blockIdx.x, tid = threadIdx.x;
    int lane = tid & 63, wv = tid >> 6;
    const float* g0 = Gp + (long)r * GRUN;
    float s = 0.f, q = 0.f;
#pragma unroll
    for (int i = 0; i < 3; ++i) {
        int col = (tid + i * 1024) * 4;
        f32x4 v = *reinterpret_cast<const f32x4*>(g0 + col);
        v += *reinterpret_cast<const f32x4*>(g0 + 393216 + col);
        v += *reinterpret_cast<const f32x4*>(g0 + 786432 + col);
        v += *reinterpret_cast<const f32x4*>(g0 + 1179648 + col);
        *reinterpret_cast<f32x4*>(gsh + col) = v;
#pragma unroll
        for (int j = 0; j < 4; ++j) { s += v[j]; q += v[j] * v[j]; }
    }
#pragma unroll
    for (int m = 1; m < 64; m <<= 1) { s += __shfl_xor(s, m); q += __shfl_xor(q, m); }
    if (lane == 0) { red[wv] = s; red[16 + wv] = q; }
    __syncthreads();
    float fs = 0.f, fq = 0.f;
#pragma unroll
    for (int i = 0; i < 16; ++i) { fs += red[i]; fq += red[16 + i]; }
    float mean = fs * (1.f / 12288.f);
    float rstd = rsqrtf(fq * (1.f / 12288.f) - mean * mean + 1e-3f);
    long orow = (long)r * T_ + t;
#pragma unroll
    for (int it = 0; it < 2; ++it) {
        int j = tid * 2 + it * 2048;
        float2 rr = *reinterpret_cast<const float2*>(gsh + j);
        float2 cc = *reinterpret_cast<const float2*>(gsh + 4096 + j);
        float2 uu = *reinterpret_cast<const float2*>(gsh + 8192 + j);
        float2 dd = *reinterpret_cast<const float2*>(deterf + (long)r * DETER_ + j);
        float dn[2]; unsigned short db[2];
#pragma unroll
        for (int i = 0; i < 2; ++i) {
            float gv = (i == 0) ? rr.x : rr.y;
            float cv = (i == 0) ? cc.x : cc.y;
            float uv = (i == 0) ? uu.x : uu.y;
            float dv = (i == 0) ? dd.x : dd.y;
            float lr = (gv - mean) * rstd * g_gru[j + i] + b_gru[j + i];
            float lc = (cv - mean) * rstd * g_gru[4096 + j + i] + b_gru[4096 + j + i];
            float lu = (uv - mean) * rstd * g_gru[8192 + j + i] + b_gru[8192 + j + i];
            float reset = sigmoidf_(lr);
            float cand = tanhf_(reset * lc);
            float upd = sigmoidf_(lu - 1.f);
            dn[i] = upd * cand + (1.f - upd) * dv;
            db[i] = f2bf(dn[i]);
        }
        float2 nd; nd.x = dn[0]; nd.y = dn[1];
        *reinterpret_cast<float2*>(deterf + (long)r * DETER_ + j) = nd;
        unsigned pk = (unsigned)db[0] | ((unsigned)db[1] << 16);
        *reinterpret_cast<unsigned*>(deterb + (long)r * DETER_ + j) = pk;
        *reinterpret_cast<unsigned*>(deter_allb + orow * DETER_ + j) = pk;
        *reinterpret_cast<float2*>(out + orow * 10240 + j) = nd;
    }
}

// ---------------- h GEMM, K-split 4 (R4-verified) ----------------
__global__ __launch_bounds__(256) void k_h4(
    const unsigned short* __restrict__ Wood,
    const unsigned short* __restrict__ deterb,
    float* __restrict__ hpart)
{
    __shared__ __align__(16) unsigned short sb[2][32 * 512];
    __shared__ float s_out[32][66];
    int tid = threadIdx.x, lane = tid & 63, wv = tid >> 6;
    int c = lane & 15, kb = lane >> 4;
    int n = blockIdx.x, kq = blockIdx.y;
    const unsigned short* bbase = Wood + ((long)(n * 4 + wv) * 128) * 512 + lane * 8;
    f32x4 acc0 = {0,0,0,0}, acc1 = {0,0,0,0};
    stage_glds<512>(sb[0], deterb, 4096, (long)kq * 1024);
    stage_glds<512>(sb[1], deterb, 4096, (long)kq * 1024 + 512);
    vmwaitN<8>(); barrier_();
    mfma2<512>(sb[0], c, kb, bbase + (long)(kq * 32) * 512, acc0, acc1);
    vmwaitN<0>(); barrier_();
    mfma2<512>(sb[1], c, kb, bbase + (long)(kq * 32 + 16) * 512, acc0, acc1);
    __syncthreads();
#pragma unroll
    for (int j = 0; j < 4; ++j) {
        s_out[kb * 4 + j][wv * 16 + c] = acc0[j];
        s_out[16 + kb * 4 + j][wv * 16 + c] = acc1[j];
    }
    __syncthreads();
    int row = tid >> 3, c8 = (tid & 7) * 8;
    float* hp = hpart + (long)kq * 32768 + (long)row * 1024 + n * 64 + c8;
#pragma unroll
    for (int i = 0; i < 8; ++i) hp[i] = s_out[row][c8 + i];
}

// ---------------- posterior stats + sample (R4-verified) ----------------
__global__ __launch_bounds__(256) void k_statsq2(
    const unsigned short* __restrict__ Bp, const float* __restrict__ hpart,
    const float* __restrict__ E_pre,
    const float* __restrict__ g_oo, const float* __restrict__ b_oo,
    const float* __restrict__ bias,
    const float* __restrict__ noise, float* __restrict__ out,
    unsigned short* __restrict__ stochb, int t)
{
    __shared__ __align__(16) unsigned short sb[2][32 * 512];
    __shared__ float s_out[32][66];
    __shared__ float s_mean[32], s_rstd[32];
    int tid = threadIdx.x, lane = tid & 63, wv = tid >> 6;
    int c = lane & 15, kb = lane >> 4;
    {
        int row = tid >> 3, c0 = (tid & 7) * 128;
        const float* h0 = hpart + (long)row * 1024 + c0;
        const float* ep = E_pre + ((long)row * T_ + t) * 1024 + c0;
        float s = 0.f, q = 0.f;
#pragma unroll 8
        for (int kk = 0; kk < 128; kk += 4) {
            f32x4 v = *reinterpret_cast<const f32x4*>(h0 + kk);
            v += *reinterpret_cast<const f32x4*>(h0 + 32768 + kk);
            v += *reinterpret_cast<const f32x4*>(h0 + 65536 + kk);
            v += *reinterpret_cast<const f32x4*>(h0 + 98304 + kk);
            v += *reinterpret_cast<const f32x4*>(ep + kk);
#pragma unroll
            for (int j2 = 0; j2 < 4; ++j2) { s += v[j2]; q += v[j2] * v[j2]; }
        }
#pragma unroll
        for (int m = 1; m < 8; m <<= 1) { s += __shfl_xor(s, m); q += __shfl_xor(q, m); }
        if ((tid & 7) == 0) {
            float mm = s * (1.f / 1024.f);
            s_mean[row] = mm;
            s_rstd[row] = rsqrtf(q * (1.f / 1024.f) - mm * mm + 1e-3f);
        }
    }
    __syncthreads();
    int part = wv >> 1, nt = wv & 1;
    long ntg = (long)part * 64 + blockIdx.x * 2 + nt;
    const unsigned short* bbase = Bp + ntg * 32 * 512 + lane * 8;
    f32x4 acc0 = {0,0,0,0}, acc1 = {0,0,0,0};
    stage_lnsum(sb[0], hpart, E_pre, t, 0, g_oo, b_oo, s_mean, s_rstd);
    stage_lnsum(sb[1], hpart, E_pre, t, 512, g_oo, b_oo, s_mean, s_rstd);
    lgkmwait_(); barrier_();
    mfma2<512>(sb[0], c, kb, bbase, acc0, acc1);
    mfma2<512>(sb[1], c, kb, bbase + 16 * 512, acc0, acc1);
    __syncthreads();
    float bv = bias[ntg * 16 + c];
#pragma unroll
    for (int j = 0; j < 4; ++j) {
        s_out[kb * 4 + j][part * 32 + nt * 16 + c] = acc0[j] + bv;
        s_out[16 + kb * 4 + j][part * 32 + nt * 16 + c] = acc1[j] + bv;
    }
    __syncthreads();
    int r = tid >> 3, j0 = (tid & 7) * 4;
    long orow = (long)r * T_ + t;
#pragma unroll
    for (int i = 0; i < 4; ++i) {
        int j = j0 + i;
        float mean = s_out[r][j];
        float sd = softplusf_(s_out[r][32 + j]) + 0.1f;
        int cg2 = blockIdx.x * 32 + j;
        float st = mean + sd * noise[orow * 1024 + cg2];
        float* op = out + orow * 10240;
        op[4096 + cg2] = st; op[5120 + cg2] = mean; op[6144 + cg2] = sd;
        stochb[(long)r * 1024 + cg2] = f2bf(st);
    }
}

// ---------------- batched prior (off critical path; R4-verified) ----------------
__global__ __launch_bounds__(256) void k_bstats(
    const unsigned short* __restrict__ Bp, const unsigned short* __restrict__ h_pb,
    const float* __restrict__ bias, const float* __restrict__ noise,
    float* __restrict__ out)
{
    __shared__ __align__(16) unsigned short sb[2][32 * 512];
    __shared__ float s_out[32][66];
    int tid = threadIdx.x;
    int lane = tid & 63, wv = tid >> 6;
    int part = wv >> 1, nt = wv & 1;
    int c = lane & 15, kb = lane >> 4;
    int s_ = blockIdx.x, rowbase = blockIdx.y * 32;
    const unsigned short* A = h_pb + (long)rowbase * 1024;
    long ntg = (long)part * 64 + s_ * 2 + nt;
    const unsigned short* bbase = Bp + ntg * 32 * 512 + lane * 8;
    f32x4 acc0 = {0.f,0.f,0.f,0.f}, acc1 = {0.f,0.f,0.f,0.f};
    stage_glds<512>(sb[0], A, 1024, 0);
    stage_glds<512>(sb[1], A, 1024, 512);
    vmwaitN<8>(); barrier_();
    mfma_rh<512>(sb[0], c, kb, bbase, acc0);
    mfma_rh<512>(sb[0], 16 + c, kb, bbase, acc1);
    vmwaitN<0>(); barrier_();
    mfma_rh<512>(sb[1], c, kb, bbase + 16 * 512, acc0);
    mfma_rh<512>(sb[1], 16 + c, kb, bbase + 16 * 512, acc1);
    __syncthreads();
    float bv = bias[ntg * 16 + c];
#pragma unroll
    for (int j = 0; j < 4; ++j) {
        s_out[kb * 4 + j][part * 32 + nt * 16 + c] = acc0[j] + bv;
        s_out[16 + kb * 4 + j][part * 32 + nt * 16 + c] = acc1[j] + bv;
    }
    __syncthreads();
    int r = tid >> 3, j0 = (tid & 7) * 4;
    long orow = rowbase + r;
#pragma unroll
    for (int i = 0; i < 4; ++i) {
        int j = j0 + i;
        float mean = s_out[r][j];
        float sd = softplusf_(s_out[r][32 + j]) + 0.1f;
        int cg2 = s_ * 32 + j;
        float st = mean + sd * noise[orow * 1024 + cg2];
        float* op = out + orow * 10240;
        op[7168 + cg2] = st; op[8192 + cg2] = mean; op[9216 + cg2] = sd;
    }
}

__global__ __launch_bounds__(256) void k_bfin(const float* __restrict__ hp_raw,
                                              const float* __restrict__ pbh,
                                              const float* __restrict__ g_io,
                                              const float* __restrict__ b_io,
                                              unsigned short* __restrict__ h_pb) {
    int row = blockIdx.x * 8 + ((int)threadIdx.x >> 5);
    int l = threadIdx.x & 31;
    float s = pbh[((long)l * 2048 + row) * 2];
    float q = pbh[((long)l * 2048 + row) * 2 + 1];
#pragma unroll
    for (int m = 16; m; m >>= 1) { s += __shfl_xor(s, m, 32); q += __shfl_xor(q, m, 32); }
    float mn = s * (1.f / 1024.f);
    float rs = rsqrtf(q * (1.f / 1024.f) - mn * mn + 1e-3f);
#pragma unroll
    for (int i = 0; i < 8; ++i) {
        int col = i * 128 + l * 4;
        f32x4 v = *reinterpret_cast<const f32x4*>(hp_raw + (long)row * 1024 + col);
        unsigned short pk[4];
#pragma unroll
        for (int j = 0; j < 4; ++j) {
            float ln = (v[j] - mn) * rs * g_io[col + j] + b_io[col + j];
            pk[j] = f2bf(siluf_(ln));
        }
        *reinterpret_cast<u16x4*>(h_pb + (long)row * 1024 + col) = *reinterpret_cast<u16x4*>(pk);
    }
}

// ---------------- host ----------------

extern "C" void kernel_launch(void* const* d_in, const int* in_sizes, int n_in,
                              void* d_out, int out_size, void* d_ws, size_t ws_size,
                              hipStream_t stream) {
    const float* embed      = (const float*)d_in[0];
    const float* action     = (const float*)d_in[1];
    const float* init_deter = (const float*)d_in[3];
    const float* init_stoch = (const float*)d_in[4];
    const float* noise_pr   = (const float*)d_in[5];
    const float* noise_po   = (const float*)d_in[6];
    const float* W_in       = (const float*)d_in[7];
    const float* g_in       = (const float*)d_in[8];
    const float* b_in       = (const float*)d_in[9];
    const float* W_gru      = (const float*)d_in[10];
    const float* g_gru      = (const float*)d_in[11];
    const float* b_gru      = (const float*)d_in[12];
    const float* W_io       = (const float*)d_in[13];
    const float* g_io       = (const float*)d_in[14];
    const float* b_io       = (const float*)d_in[15];
    const float* W_oo       = (const float*)d_in[16];
    const float* g_oo       = (const float*)d_in[17];
    const float* b_oo       = (const float*)d_in[18];
    const float* W_ims      = (const float*)d_in[19];
    const float* b_ims      = (const float*)d_in[20];
    const float* W_obs      = (const float*)d_in[21];
    const float* b_obs      = (const float*)d_in[22];
    float* out = (float*)d_out;

    char* ws = (char*)d_ws;
    size_t off = 0;
    auto alloc = [&](size_t bytes) {
        size_t r = off;
        off = (off + bytes + 255) & ~(size_t)255;
        return r;
    };
    unsigned short* pWgru  = (unsigned short*)(ws + alloc((size_t)5120 * 12288 * 2));
    unsigned short* pWin_s = (unsigned short*)(ws + alloc((size_t)1024 * 1024 * 2));
    unsigned short* pWin_a = (unsigned short*)(ws + alloc((size_t)128 * 1024 * 2));
    unsigned short* pWio   = (unsigned short*)(ws + alloc((size_t)4096 * 1024 * 2));
    unsigned short* pWood  = (unsigned short*)(ws + alloc((size_t)4096 * 1024 * 2));
    unsigned short* pWooe  = (unsigned short*)(ws + alloc((size_t)1536 * 1024 * 2));
    unsigned short* pWims  = (unsigned short*)(ws + alloc((size_t)1024 * 2048 * 2));
    unsigned short* pWobs  = (unsigned short*)(ws + alloc((size_t)1024 * 2048 * 2));
    unsigned short* act_bf = (unsigned short*)(ws + alloc((size_t)2048 * 128 * 2));
    unsigned short* emb_bf = (unsigned short*)(ws + alloc((size_t)2048 * 1536 * 2));
    float* A_pre  = (float*)(ws + alloc((size_t)2048 * 1024 * 4));
    float* E_pre  = (float*)(ws + alloc((size_t)2048 * 1024 * 4));
    float* x_raw  = (float*)(ws + alloc((size_t)32 * 1024 * 4));
    float* Gp     = (float*)(ws + alloc((size_t)4 * 32 * GRUN * 4));
    float* deterf = (float*)(ws + alloc((size_t)32 * DETER_ * 4));
    unsigned short* deterb     = (unsigned short*)(ws + alloc((size_t)32 * DETER_ * 2));
    unsigned short* deter_allb = (unsigned short*)(ws + alloc((size_t)2048 * DETER_ * 2));
    unsigned short* stochb = (unsigned short*)(ws + alloc((size_t)32 * 1024 * 2));
    float* hp_raw = (float*)(ws + alloc((size_t)2048 * 1024 * 4));
    unsigned short* h_pb = (unsigned short*)(ws + alloc((size_t)2048 * 1024 * 2));
    float* px  = (float*)(ws + alloc((size_t)32 * 32 * 2 * 4));
    float* pbh = (float*)(ws + alloc((size_t)32 * 2048 * 2 * 4));
    float* hpart = (float*)(ws + alloc((size_t)4 * 32 * 1024 * 4));
    (void)ws_size; (void)out_size; (void)n_in; (void)in_sizes;

    auto packgrid = [](long K, long N) { return (unsigned)((K * N / 8 + 255) / 256); };

    // prep: pack weights
    k_pack<<<packgrid(5120, 12288), 256, 0, stream>>>(W_gru, pWgru, 5120, 12288);
    k_pack<<<packgrid(1024, 1024), 256, 0, stream>>>(W_in, pWin_s, 1024, 1024);
    k_pack<<<packgrid(128, 1024), 256, 0, stream>>>(W_in + (size_t)1024 * 1024, pWin_a, 128, 1024);
    k_pack<<<packgrid(4096, 1024), 256, 0, stream>>>(W_io, pWio, 4096, 1024);
    k_pack<<<packgrid(4096, 1024), 256, 0, stream>>>(W_oo, pWood, 4096, 1024);
    k_pack<<<packgrid(1536, 1024), 256, 0, stream>>>(W_oo + (size_t)4096 * 1024, pWooe, 1536, 1024);
    k_pack<<<packgrid(1024, 2048), 256, 0, stream>>>(W_ims, pWims, 1024, 2048);
    k_pack<<<packgrid(1024, 2048), 256, 0, stream>>>(W_obs, pWobs, 1024, 2048);
    // prep: conversions
    k_conv<<<(2048 * 128 / 4 + 255) / 256, 256, 0, stream>>>(action, act_bf, 2048L * 128);
    k_conv<<<(2048 * 1536 / 4 + 255) / 256, 256, 0, stream>>>(embed, emb_bf, 2048L * 1536);
    k_conv<<<(32 * 1024 / 4 + 255) / 256, 256, 0, stream>>>(init_stoch, stochb, 32L * 1024);
    k_conv<<<(32 * 4096 / 4 + 255) / 256, 256, 0, stream>>>(init_deter, deterb, 32L * 4096);
    k_copy<<<(32 * 4096 / 4 + 255) / 256, 256, 0, stream>>>(init_deter, deterf, 32L * 4096);
    // prep: time-invariant contributions  A_pre = act@Win_a ; E_pre = emb@Wooe
    k_gemm32<128, 1, 0><<<dim3(32, 64), 256, 0, stream>>>(
        pWin_a, 4, 0, act_bf, 128, nullptr, 0, nullptr, nullptr, nullptr, 0,
        nullptr, 0, A_pre, 1024, nullptr, 0);
    k_gemm32<512, 3, 0><<<dim3(32, 64), 256, 0, stream>>>(
        pWooe, 48, 0, emb_bf, 1536, nullptr, 0, nullptr, nullptr, nullptr, 0,
        nullptr, 0, E_pre, 1024, nullptr, 0);

    for (int t = 0; t < T_; ++t) {
        // x_raw = stoch@Win_s + A_pre[t]
        k_gemm32<512, 2, 0><<<dim3(32, 1), 256, 0, stream>>>(
            pWin_s, 32, 0, stochb, 1024, nullptr, 0, nullptr, nullptr, nullptr, 0,
            A_pre + (size_t)t * 1024, (long)T_ * 1024, x_raw, 1024, px, 32);
        // Gp[kq] = partial [silu(LN(x)) | deter] @ Wgru, K-split 4, CW=256
        k_gru4<<<dim3(192, 4), 256, 0, stream>>>(pWgru, deterb, x_raw, px, g_in, b_in, Gp);
        // sum quarters, LN, gates -> deter
        k_deter4<<<32, 1024, 0, stream>>>(Gp, g_gru, b_gru, deterf, deterb,
                                          deter_allb, out, t);
        // hpart[kq] = deter-slice @ Wood-slice
        k_h4<<<dim3(16, 4), 256, 0, stream>>>(pWood, deterb, hpart);
        // posterior stats + sample
        k_statsq2<<<32, 256, 0, stream>>>(pWobs, hpart, E_pre, g_oo, b_oo, b_obs,
                                          noise_po, out, stochb, t);
    }

    // batched prior chain (off critical path)
    k_gemm32<512, 8, 0><<<dim3(32, 64), 256, 0, stream>>>(
        pWio, 128, 0, deter_allb, 4096, nullptr, 0, nullptr, nullptr, nullptr, 0,
        nullptr, 0, hp_raw, 1024, pbh, 2048);
    k_bfin<<<256, 256, 0, stream>>>(hp_raw, pbh, g_io, b_io, h_pb);
    k_bstats<<<dim3(32, 64), 256, 0, stream>>>(pWims, h_pb, b_ims, noise_pr, out);
}